// Round 10
// baseline (138.905 us; speedup 1.0000x reference)
//
#include <hip/hip_runtime.h>
#include <math.h>

#define NS   16
#define CIN  3
#define CF   32
#define CROP 256
#define KH   129

typedef _Float16 half8  __attribute__((ext_vector_type(8)));
typedef _Float16 half4v __attribute__((ext_vector_type(4)));
typedef _Float16 half2v __attribute__((ext_vector_type(2)));
typedef float    f32x4  __attribute__((ext_vector_type(4)));
typedef unsigned int u32x4 __attribute__((ext_vector_type(4)));

// exact negation of 8 packed f16 (sign-bit xor); split planes negate exactly
__device__ __forceinline__ half8 neg8(half8 v) {
    u32x4 u = __builtin_bit_cast(u32x4, v);
    u ^= (u32x4){0x80008000u, 0x80008000u, 0x80008000u, 0x80008000u};
    return __builtin_bit_cast(half8, u);
}

// bijective XCD-chunked swizzle (m204)
__device__ __forceinline__ int swz8(int b, int nb) {
    int q = nb >> 3, r = nb & 7;
    int x = b & 7, o = b >> 3;
    return (x < r ? x * (q + 1) : r * (q + 1) + (x - r) * q) + o;
}

// ---------------- LDS layout for fused_features (bytes) -------------------
#define X_OFF 0
#define Z_OFF 21504
#define LDS_BYTES 23904

__device__ __forceinline__ int xaddr(int q, int s) {
    return X_OFF + (q << 6) + ((s ^ ((q >> 1) & 3)) << 4);
}

// channel permutation: row position p <- channel c.
__device__ __forceinline__ int pi_of(int co) {
    int h = co >> 3, j = co & 7;
    return (j < 4) ? (h * 4 + j) : (16 + h * 4 + j - 4);
}
__device__ __forceinline__ int cinv_of(int p) {
    int h = (p & 15) >> 2;
    int j = (p & 3) + ((p >= 16) ? 4 : 0);
    return h * 8 + j;
}

__device__ __forceinline__ void split_pair(float v0, float v1,
                                           half2v* hp, half2v* lp) {
    _Float16 h0 = (_Float16)v0, h1 = (_Float16)v1;
    *hp = (half2v){h0, h1};
    *lp = (half2v){(_Float16)(v0 - (float)h0), (_Float16)(v1 - (float)h1)};
}

// ---------------------------------------------------------------------------
// prep: twiddle tables via 256-entry LDS cos/sin lookup, pair-packed stores.
// 1024 pairs/block. blocks: [0,34) TA | [34,98) G1,G3 | [98,134) TC | [134,137) w
// ---------------------------------------------------------------------------
__global__ __launch_bounds__(256)
void prep(const float* __restrict__ w1, const float* __restrict__ w2,
          _Float16* __restrict__ w1pk, _Float16* __restrict__ w2lin,
          _Float16* __restrict__ TAh, _Float16* __restrict__ TAl,
          _Float16* __restrict__ G1h, _Float16* __restrict__ G1l,
          _Float16* __restrict__ G3h, _Float16* __restrict__ G3l,
          _Float16* __restrict__ TCh, _Float16* __restrict__ TCl)
{
    const int bid = blockIdx.x, tid = threadIdx.x;

    if (bid >= 134) {             // ---- weight prepack (permuted rows) ----
        int base = (bid - 134) * 4096;
        #pragma unroll
        for (int i = 0; i < 16; ++i) {
            int e = base + tid + i * 256;
            if (e < 9216) {       // w2[co][ci][k9] -> w2lin[k9][pi(co)][ci]
                int co = e / 288;
                int r  = e - co * 288;
                int ci = r / 9, k9 = r - ci * 9;
                w2lin[(k9 * 32 + pi_of(co)) * 32 + ci] = (_Float16)w2[e];
            } else if (e < 9344) {
                int t = e - 9216;             // cg*64 + lane
                int lane = t & 63;
                int p = (t >> 6) * 16 + (lane & 15);
                int c = cinv_of(p);
                #pragma unroll
                for (int j = 0; j < 8; ++j) {
                    int k = ((lane >> 4) << 3) + j;
                    w1pk[t * 8 + j] = (k < 27) ? (_Float16)w1[c * 27 + k]
                                               : (_Float16)0.f;
                }
            }
        }
        return;
    }

    __shared__ float cs[256], sn[256];
    {
        float s, c;
        sincosf(0.02454369260617025967f * (float)tid, &s, &c);  // 2*pi/256
        cs[tid] = c; sn[tid] = s;
    }
    __syncthreads();

    // pair index p: elem e = 2p; j0 = (p&3)*2, lane = (p>>2)&63, q = p>>8
    if (bid < 34) {               // ---- TA: 34816 pairs, 1024/block ----
        int base = bid * 1024 + tid;
        #pragma unroll
        for (int i = 0; i < 4; ++i) {
            int p = base + i * 256;
            int j0 = (p & 3) * 2, lane = (p >> 2) & 63, q = p >> 8;
            int nt = q % 17, ks = q / 17;
            int x0 = ks * 32 + ((lane >> 4) << 3) + j0;
            int c = nt * 16 + (lane & 15);
            float v0 = 0.f, v1 = 0.f;
            if (c <= 128) {
                v0 =  cs[(x0 * c) & 255];
                v1 =  cs[((x0 + 1) * c) & 255];
            } else if (c >= 136 && c <= 264) {
                int cc = c - 136;
                v0 = -sn[(x0 * cc) & 255];
                v1 = -sn[((x0 + 1) * cc) & 255];
            }
            half2v hv, lv; split_pair(v0, v1, &hv, &lv);
            ((half2v*)TAh)[p] = hv; ((half2v*)TAl)[p] = lv;
        }
    } else if (bid < 98) {        // ---- G1,G3: 65536 pairs ----
        int base = (bid - 34) * 1024 + tid;
        #pragma unroll
        for (int i = 0; i < 4; ++i) {
            int p = base + i * 256;
            int j0 = (p & 3) * 2, lane = (p >> 2) & 63, q = p >> 8;
            int nt = q & 15, ks = q >> 4;
            int kk0 = ks * 32 + ((lane >> 4) << 3) + j0;
            int m  = nt * 16 + (lane & 15);
            int part = kk0 >> 8;                    // uniform for the pair
            int y0 = kk0 & 255;
            int i0 = (y0 * m) & 255, i1 = ((y0 + 1) * m) & 255;
            float cv0 = cs[i0], s0 = sn[i0], cv1 = cs[i1], s1 = sn[i1];
            half2v hv, lv;
            float a0 = part ? s0 : cv0,  a1 = part ? s1 : cv1;          // G1
            split_pair(a0, a1, &hv, &lv);
            ((half2v*)G1h)[p] = hv; ((half2v*)G1l)[p] = lv;
            a0 = (part ? -s0 : cv0) * (1.f/256.f);                      // G3
            a1 = (part ? -s1 : cv1) * (1.f/256.f);
            split_pair(a0, a1, &hv, &lv);
            ((half2v*)G3h)[p] = hv; ((half2v*)G3l)[p] = lv;
        }
    } else {                      // ---- TC: 36864 pairs ----
        int base = (bid - 98) * 1024 + tid;
        #pragma unroll
        for (int i = 0; i < 4; ++i) {
            int p = base + i * 256;
            int j0 = (p & 3) * 2, lane = (p >> 2) & 63, q = p >> 8;
            int nt = q & 15, ks = q >> 4;
            int kk0 = ks * 32 + ((lane >> 4) << 3) + j0;
            int x  = nt * 16 + (lane & 15);
            int part = (kk0 >= 144) ? 1 : 0;        // pair never straddles
            int k0 = kk0 - part * 144;
            float v0 = 0.f, v1 = 0.f;
            if (k0 <= 128) {
                float w0 = (k0 == 0 || k0 == 128) ? 1.f : 2.f;
                int ii = (k0 * x) & 255;
                v0 = (part ? -w0 * sn[ii] : w0 * cs[ii]) * (1.f/256.f);
            }
            int k1 = k0 + 1;
            if (k1 <= 128) {
                float w1w = (k1 == 0 || k1 == 128) ? 1.f : 2.f;
                int ii = (k1 * x) & 255;
                v1 = (part ? -w1w * sn[ii] : w1w * cs[ii]) * (1.f/256.f);
            }
            half2v hv, lv; split_pair(v0, v1, &hv, &lv);
            ((half2v*)TCh)[p] = hv; ((half2v*)TCl)[p] = lv;
        }
    }
}

// ---------------------------------------------------------------------------
// Kernel 1: fused conv1+ReLU -> conv2 -> LRN -> *cos_window -> channel sum
// (round-5/8 measured-best; launch_bounds min-waves bumped 5->6)
// ---------------------------------------------------------------------------
__global__ __launch_bounds__(256, 6)
void fused_features(const float* __restrict__ z,
                    const _Float16* __restrict__ w1pk,
                    const float* __restrict__ b1,
                    const _Float16* __restrict__ w2lin,
                    const float* __restrict__ b2,
                    const float* __restrict__ cosw,
                    _Float16* __restrict__ g2h, _Float16* __restrict__ g2l)
{
    __shared__ __align__(16) unsigned char smem[LDS_BYTES];
    _Float16* ztile = (_Float16*)(smem + Z_OFF);

    const int tid  = threadIdx.x;
    const int lane = tid & 63;
    const int wv   = tid >> 6;
    const int l15  = lane & 15;
    const int lhi  = lane >> 4;

    const int n  = blockIdx.z;
    const int bx = blockIdx.x, by = blockIdx.y;
    const int fy0 = by * 16 - 1;
    const int fx0 = bx * 16 - 1;

    const int zy0 = by * 16 - 2;
    const int zx0 = bx * 16 - 2;
    for (int idx = tid; idx < CIN * 400; idx += 256) {
        int ci = idx / 400;
        int r  = idx - ci * 400;
        int yy = r / 20, xx = r - yy * 20;
        int gy = zy0 + yy, gx = zx0 + xx;
        float v = 0.0f;
        if ((unsigned)gy < CROP && (unsigned)gx < CROP)
            v = z[((n * CIN + ci) * CROP + gy) * CROP + gx];
        ztile[idx] = (_Float16)v;
    }

    half8 w1f0 = *(const half8*)(w1pk + lane * 8);
    half8 w1f1 = *(const half8*)(w1pk + 512 + lane * 8);
    float bias1v[2][4], bias2v[2][4];
    #pragma unroll
    for (int cg = 0; cg < 2; ++cg)
        #pragma unroll
        for (int r = 0; r < 4; ++r) {
            bias1v[cg][r] = b1[8 * lhi + 4 * cg + r];
            bias2v[cg][r] = b2[8 * lhi + 4 * cg + r];
        }

    int offs[8];
    #pragma unroll
    for (int j = 0; j < 8; ++j) {
        int k = lhi * 8 + j;
        int ci = k / 9, rr = k - ci * 9;
        int ky = rr / 3, kx = rr - ky * 3;
        offs[j] = (k < 27) ? (ci * 400 + ky * 20 + kx) : 0;
    }
    __syncthreads();

    const f32x4 zero4 = {0.f, 0.f, 0.f, 0.f};
    for (int t = wv; t < 21; t += 4) {
        int qp = t * 16 + l15;
        int qpc = qp < 324 ? qp : 323;
        int y = qpc / 18, x = qpc - y * 18;
        const _Float16* zb = ztile + y * 20 + x;
        half8 bfrag;
        #pragma unroll
        for (int j = 0; j < 8; ++j) bfrag[j] = zb[offs[j]];
        f32x4 d0 = __builtin_amdgcn_mfma_f32_16x16x32_f16(w1f0, bfrag, zero4, 0, 0, 0);
        f32x4 d1 = __builtin_amdgcn_mfma_f32_16x16x32_f16(w1f1, bfrag, zero4, 0, 0, 0);
        int gy = fy0 + y, gx = fx0 + x;
        bool ok = ((unsigned)gy < CROP) && ((unsigned)gx < CROP) && (qp < 324);
        half8 o8;
        #pragma unroll
        for (int r = 0; r < 4; ++r) {
            float v0 = ok ? fmaxf(d0[r] + bias1v[0][r], 0.f) : 0.f;
            float v1 = ok ? fmaxf(d1[r] + bias1v[1][r], 0.f) : 0.f;
            o8[r]     = (_Float16)v0;
            o8[4 + r] = (_Float16)v1;
        }
        *(half8*)(smem + xaddr(qp, lhi)) = o8;
    }
    __syncthreads();

    f32x4 acc[4][2];
    #pragma unroll
    for (int tt = 0; tt < 4; ++tt)
        #pragma unroll
        for (int cg = 0; cg < 2; ++cg)
            #pragma unroll
            for (int r = 0; r < 4; ++r)
                acc[tt][cg][r] = bias2v[cg][r];

    #pragma unroll
    for (int k9 = 0; k9 < 9; ++k9) {
        const int ky = k9 / 3, kx = k9 - 3 * ky;
        half8 af0 = *(const half8*)(w2lin + (k9 * 32 + l15)      * 32 + lhi * 8);
        half8 af1 = *(const half8*)(w2lin + (k9 * 32 + l15 + 16) * 32 + lhi * 8);
        #pragma unroll
        for (int tt = 0; tt < 4; ++tt) {
            int q = (wv * 4 + tt + ky) * 18 + l15 + kx;
            half8 bf = *(const half8*)(smem + xaddr(q, lhi));
            acc[tt][0] = __builtin_amdgcn_mfma_f32_16x16x32_f16(af0, bf, acc[tt][0], 0, 0, 0);
            acc[tt][1] = __builtin_amdgcn_mfma_f32_16x16x32_f16(af1, bf, acc[tt][1], 0, 0, 0);
        }
    }

    const bool bot = (lhi == 0), top = (lhi == 3);
    #pragma unroll
    for (int tt = 0; tt < 4; ++tt) {
        float aA0 = acc[tt][0][0], aA1 = acc[tt][0][1],
              aA2 = acc[tt][0][2], aA3 = acc[tt][0][3];
        float aB0 = acc[tt][1][0], aB1 = acc[tt][1][1],
              aB2 = acc[tt][1][2], aB3 = acc[tt][1][3];
        float sA0 = aA0 * aA0, sA1 = aA1 * aA1, sA2 = aA2 * aA2, sA3 = aA3 * aA3;
        float sB0 = aB0 * aB0, sB1 = aB1 * aB1, sB2 = aB2 * aB2, sB3 = aB3 * aB3;
        int up = (lane + 16) & 63, dn = (lane + 48) & 63;
        float em2 = __shfl(sB2, dn); em2 = bot ? 0.f : em2;
        float em1 = __shfl(sB3, dn); em1 = bot ? 0.f : em1;
        float ep8 = __shfl(sA0, up); ep8 = top ? 0.f : ep8;
        float ep9 = __shfl(sA1, up); ep9 = top ? 0.f : ep9;
        float s = 0.f, win = em2 + em1 + sA0 + sA1 + sA2;
        float t2, f;
        t2 = 2e-5f * win; f = fmaf(t2, fmaf(t2, 0.65625f, -0.75f), 1.0f);
        s = fmaf(aA0, f, s);  win += sA3 - em2;
        t2 = 2e-5f * win; f = fmaf(t2, fmaf(t2, 0.65625f, -0.75f), 1.0f);
        s = fmaf(aA1, f, s);  win += sB0 - em1;
        t2 = 2e-5f * win; f = fmaf(t2, fmaf(t2, 0.65625f, -0.75f), 1.0f);
        s = fmaf(aA2, f, s);  win += sB1 - sA0;
        t2 = 2e-5f * win; f = fmaf(t2, fmaf(t2, 0.65625f, -0.75f), 1.0f);
        s = fmaf(aA3, f, s);  win += sB2 - sA1;
        t2 = 2e-5f * win; f = fmaf(t2, fmaf(t2, 0.65625f, -0.75f), 1.0f);
        s = fmaf(aB0, f, s);  win += sB3 - sA2;
        t2 = 2e-5f * win; f = fmaf(t2, fmaf(t2, 0.65625f, -0.75f), 1.0f);
        s = fmaf(aB1, f, s);  win += ep8 - sA3;
        t2 = 2e-5f * win; f = fmaf(t2, fmaf(t2, 0.65625f, -0.75f), 1.0f);
        s = fmaf(aB2, f, s);  win += ep9 - sB0;
        t2 = 2e-5f * win; f = fmaf(t2, fmaf(t2, 0.65625f, -0.75f), 1.0f);
        s = fmaf(aB3, f, s);
        s += __shfl_xor(s, 16);
        s += __shfl_xor(s, 32);
        if (lhi == 0) {
            int gy = by * 16 + wv * 4 + tt, gx = bx * 16 + l15;
            float val = s * cosw[gy * CROP + gx];
            _Float16 h = (_Float16)val;
            int o = (n * CROP + gy) * CROP + gx;
            g2h[o] = h;
            g2l[o] = (_Float16)(val - (float)h);
        }
    }
}

// ---------------------------------------------------------------------------
// Stage A: row rfft. SPLIT-K: 2 waves per unit (kh=0: ks0..3, kh=1: ks4..7),
// LDS partial exchange. 2176 blocks (2 units x 2 kh per block), XCD-chunked.
// ---------------------------------------------------------------------------
__global__ __launch_bounds__(256, 4)
void fft_rows(const _Float16* __restrict__ g2h, const _Float16* __restrict__ g2l,
              const _Float16* __restrict__ TAh, const _Float16* __restrict__ TAl,
              _Float16* __restrict__ Zth, _Float16* __restrict__ Ztl)
{
    __shared__ f32x4 part[2][3][64];
    const int lane = threadIdx.x & 63;
    const int w = threadIdx.x >> 6;
    const int u = w >> 1, kh = w & 1;
    const int bsw = swz8(blockIdx.x, 2176);
    const int unit = bsw * 2 + u;                         // 0..4351
    const int mt = unit / 17, nt = unit - mt * 17;
    const int l15 = lane & 15, lhi = lane >> 4;
    const int rowA = mt * 16 + l15;

    f32x4 a0 = {}, a1 = {}, a2 = {};
    #pragma unroll
    for (int i = 0; i < 4; ++i) {
        const int ks = kh * 4 + i;
        const int ao = rowA * 256 + ks * 32 + lhi * 8;
        half8 Ah = *(const half8*)(g2h + ao);
        half8 Al = *(const half8*)(g2l + ao);
        const int bo = ((ks * 17 + nt) * 64 + lane) * 8;
        half8 Bh = *(const half8*)(TAh + bo);
        half8 Bl = *(const half8*)(TAl + bo);
        a0 = __builtin_amdgcn_mfma_f32_16x16x32_f16(Ah, Bh, a0, 0, 0, 0);
        a1 = __builtin_amdgcn_mfma_f32_16x16x32_f16(Ah, Bl, a1, 0, 0, 0);
        a2 = __builtin_amdgcn_mfma_f32_16x16x32_f16(Al, Bh, a2, 0, 0, 0);
    }
    if (kh) {
        part[u][0][lane] = a0; part[u][1][lane] = a1; part[u][2][lane] = a2;
    }
    __syncthreads();
    if (kh) return;
    a0 += part[u][0][lane]; a1 += part[u][1][lane]; a2 += part[u][2][lane];

    f32x4 acc;
    #pragma unroll
    for (int r = 0; r < 4; ++r) acc[r] = a0[r] + a1[r] + a2[r];

    const int rowD = mt * 16 + lhi * 4;
    const int n = rowD >> 8, y = rowD & 255;
    int c = nt * 16 + l15;
    int row_k = -1, koff = 0;
    if (c <= 128)                  { row_k = c;       koff = 0;   }
    else if (c >= 136 && c <= 264) { row_k = c - 136; koff = 256; }
    if (row_k >= 0) {
        half4v hv, lv;
        #pragma unroll
        for (int r = 0; r < 4; ++r) {
            float v = acc[r];
            _Float16 h = (_Float16)v;
            hv[r] = h; lv[r] = (_Float16)(v - (float)h);
        }
        size_t o = (size_t)(n * 129 + row_k) * 512 + koff + y;
        *(half4v*)(Zth + o) = hv;
        *(half4v*)(Ztl + o) = lv;
    }
}

// ---------------------------------------------------------------------------
// Stage B1: col fft + *conj(wf[0,1]). SPLIT-K + ks-mirror. 1032 blocks.
// ---------------------------------------------------------------------------
__global__ __launch_bounds__(256, 4)
void fft_cols_mul(const _Float16* __restrict__ Zth, const _Float16* __restrict__ Ztl,
                  const _Float16* __restrict__ G1h, const _Float16* __restrict__ G1l,
                  const float* __restrict__ wf,
                  _Float16* __restrict__ Ph, _Float16* __restrict__ Pl)
{
    __shared__ f32x4 part[2][6][64];
    const int lane = threadIdx.x & 63;
    const int w = threadIdx.x >> 6;
    const int u = w >> 1, kh = w & 1;
    const int bsw = swz8(blockIdx.x, 1032);
    const int unit = bsw * 2 + u;                         // 0..2063
    const int mt = unit >> 4, nt = unit & 15;             // mt: 0..128
    const int l15 = lane & 15, lhi = lane >> 4;
    const int rowA = mt * 16 + l15;

    f32x4 r0 = {}, r1 = {}, r2 = {}, i0 = {}, i1 = {}, i2 = {};
    #pragma unroll
    for (int i = 0; i < 4; ++i) {
        const int ks = kh * 4 + i;
        const int ao0 = rowA * 512 + ks * 32 + lhi * 8;
        half8 Ah0 = *(const half8*)(Zth + ao0);
        half8 Al0 = *(const half8*)(Ztl + ao0);
        half8 Ah1 = *(const half8*)(Zth + ao0 + 256);
        half8 Al1 = *(const half8*)(Ztl + ao0 + 256);
        const int bo0 = ((ks * 16 + nt) * 64 + lane) * 8;
        half8 B0h = *(const half8*)(G1h + bo0);            // G1[ks]
        half8 B0l = *(const half8*)(G1l + bo0);
        half8 B1h_ = *(const half8*)(G1h + bo0 + 65536);   // G1[ks+8]
        half8 B1l_ = *(const half8*)(G1l + bo0 + 65536);
        half8 nB1h = neg8(B1h_), nB1l = neg8(B1l_);        // G2[ks] = -G1[ks+8]
        r0 = __builtin_amdgcn_mfma_f32_16x16x32_f16(Ah0, B0h,  r0, 0, 0, 0);
        r1 = __builtin_amdgcn_mfma_f32_16x16x32_f16(Ah0, B0l,  r1, 0, 0, 0);
        r2 = __builtin_amdgcn_mfma_f32_16x16x32_f16(Al0, B0h,  r2, 0, 0, 0);
        r0 = __builtin_amdgcn_mfma_f32_16x16x32_f16(Ah1, B1h_, r0, 0, 0, 0);
        r1 = __builtin_amdgcn_mfma_f32_16x16x32_f16(Ah1, B1l_, r1, 0, 0, 0);
        r2 = __builtin_amdgcn_mfma_f32_16x16x32_f16(Al1, B1h_, r2, 0, 0, 0);
        i0 = __builtin_amdgcn_mfma_f32_16x16x32_f16(Ah0, nB1h, i0, 0, 0, 0);
        i1 = __builtin_amdgcn_mfma_f32_16x16x32_f16(Ah0, nB1l, i1, 0, 0, 0);
        i2 = __builtin_amdgcn_mfma_f32_16x16x32_f16(Al0, nB1h, i2, 0, 0, 0);
        i0 = __builtin_amdgcn_mfma_f32_16x16x32_f16(Ah1, B0h,  i0, 0, 0, 0);
        i1 = __builtin_amdgcn_mfma_f32_16x16x32_f16(Ah1, B0l,  i1, 0, 0, 0);
        i2 = __builtin_amdgcn_mfma_f32_16x16x32_f16(Al1, B0h,  i2, 0, 0, 0);
    }
    if (kh) {
        part[u][0][lane] = r0; part[u][1][lane] = r1; part[u][2][lane] = r2;
        part[u][3][lane] = i0; part[u][4][lane] = i1; part[u][5][lane] = i2;
    }
    __syncthreads();
    if (kh) return;
    r0 += part[u][0][lane]; r1 += part[u][1][lane]; r2 += part[u][2][lane];
    i0 += part[u][3][lane]; i1 += part[u][4][lane]; i2 += part[u][5][lane];

    const int rowP0 = mt * 16 + lhi * 4;
    const int m = nt * 16 + l15;
    const float* wf1 = wf + 256 * 129 * 2;
    int n_ = rowP0 / 129;
    int k_ = rowP0 - n_ * 129;
    #pragma unroll
    for (int r = 0; r < 4; ++r) {
        float wr = wf1[(m * 129 + k_) * 2 + 0];
        float wi = wf1[(m * 129 + k_) * 2 + 1];
        float fr = r0[r] + r1[r] + r2[r];
        float fi = i0[r] + i1[r] + i2[r];
        float pr = wr * fr + wi * fi;
        float pi = wr * fi - wi * fr;
        size_t o = (size_t)(rowP0 + r) * 512 + m;
        _Float16 h;
        h = (_Float16)pr; Ph[o] = h;       Pl[o] = (_Float16)(pr - (float)h);
        h = (_Float16)pi; Ph[o + 256] = h; Pl[o + 256] = (_Float16)(pi - (float)h);
        if (++k_ == 129) { k_ = 0; ++n_; }
    }
}

// ---------------------------------------------------------------------------
// Stage B2: col ifft (1/256). SPLIT-K + R/I merged + ks-mirror. 1032 blocks.
// ---------------------------------------------------------------------------
__global__ __launch_bounds__(256, 4)
void fft_cols_inv(const _Float16* __restrict__ Ph, const _Float16* __restrict__ Pl,
                  const _Float16* __restrict__ G3h, const _Float16* __restrict__ G3l,
                  _Float16* __restrict__ Bth, _Float16* __restrict__ Btl)
{
    __shared__ f32x4 part[2][6][64];
    const int lane = threadIdx.x & 63;
    const int w = threadIdx.x >> 6;
    const int u = w >> 1, kh = w & 1;
    const int bsw = swz8(blockIdx.x, 1032);
    const int unit = bsw * 2 + u;                         // 0..2063
    const int mt = unit >> 4, nt = unit & 15;
    const int l15 = lane & 15, lhi = lane >> 4;
    const int rowA = mt * 16 + l15;

    f32x4 r0 = {}, r1 = {}, r2 = {}, i0 = {}, i1 = {}, i2 = {};
    #pragma unroll
    for (int i = 0; i < 4; ++i) {
        const int ks = kh * 4 + i;
        const int ao0 = rowA * 512 + ks * 32 + lhi * 8;
        half8 Ah0 = *(const half8*)(Ph + ao0);
        half8 Al0 = *(const half8*)(Pl + ao0);
        half8 Ah1 = *(const half8*)(Ph + ao0 + 256);
        half8 Al1 = *(const half8*)(Pl + ao0 + 256);
        const int bo0 = ((ks * 16 + nt) * 64 + lane) * 8;
        half8 B0h = *(const half8*)(G3h + bo0);            // G3[ks]
        half8 B0l = *(const half8*)(G3l + bo0);
        half8 B1h_ = *(const half8*)(G3h + bo0 + 65536);   // G3[ks+8]
        half8 B1l_ = *(const half8*)(G3l + bo0 + 65536);
        half8 nB1h = neg8(B1h_), nB1l = neg8(B1l_);        // G4[ks] = -G3[ks+8]
        r0 = __builtin_amdgcn_mfma_f32_16x16x32_f16(Ah0, B0h,  r0, 0, 0, 0);
        r1 = __builtin_amdgcn_mfma_f32_16x16x32_f16(Ah0, B0l,  r1, 0, 0, 0);
        r2 = __builtin_amdgcn_mfma_f32_16x16x32_f16(Al0, B0h,  r2, 0, 0, 0);
        r0 = __builtin_amdgcn_mfma_f32_16x16x32_f16(Ah1, B1h_, r0, 0, 0, 0);
        r1 = __builtin_amdgcn_mfma_f32_16x16x32_f16(Ah1, B1l_, r1, 0, 0, 0);
        r2 = __builtin_amdgcn_mfma_f32_16x16x32_f16(Al1, B1h_, r2, 0, 0, 0);
        i0 = __builtin_amdgcn_mfma_f32_16x16x32_f16(Ah0, nB1h, i0, 0, 0, 0);
        i1 = __builtin_amdgcn_mfma_f32_16x16x32_f16(Ah0, nB1l, i1, 0, 0, 0);
        i2 = __builtin_amdgcn_mfma_f32_16x16x32_f16(Al0, nB1h, i2, 0, 0, 0);
        i0 = __builtin_amdgcn_mfma_f32_16x16x32_f16(Ah1, B0h,  i0, 0, 0, 0);
        i1 = __builtin_amdgcn_mfma_f32_16x16x32_f16(Ah1, B0l,  i1, 0, 0, 0);
        i2 = __builtin_amdgcn_mfma_f32_16x16x32_f16(Al1, B0h,  i2, 0, 0, 0);
    }
    if (kh) {
        part[u][0][lane] = r0; part[u][1][lane] = r1; part[u][2][lane] = r2;
        part[u][3][lane] = i0; part[u][4][lane] = i1; part[u][5][lane] = i2;
    }
    __syncthreads();
    if (kh) return;
    r0 += part[u][0][lane]; r1 += part[u][1][lane]; r2 += part[u][2][lane];
    i0 += part[u][3][lane]; i1 += part[u][4][lane]; i2 += part[u][5][lane];

    const int rowP0 = mt * 16 + lhi * 4;
    const int y = nt * 16 + l15;
    int n_ = rowP0 / 129;
    int k_ = rowP0 - n_ * 129;
    #pragma unroll
    for (int r = 0; r < 4; ++r) {
        size_t base = (size_t)(n_ * 256 + y) * 288 + k_;
        float v = r0[r] + r1[r] + r2[r];
        _Float16 h = (_Float16)v;
        Bth[base] = h;  Btl[base] = (_Float16)(v - (float)h);
        float v2 = i0[r] + i1[r] + i2[r];
        _Float16 h2 = (_Float16)v2;
        Bth[base + 144] = h2;  Btl[base + 144] = (_Float16)(v2 - (float)h2);
        if (++k_ == 129) { k_ = 0; ++n_; }
    }
}

// ---------------------------------------------------------------------------
// Stage C: row irfft (1/256). SPLIT-K (kh0: ks0..4, kh1: ks5..8). 2048 blocks.
// ---------------------------------------------------------------------------
__global__ __launch_bounds__(256, 4)
void irfft_rows(const _Float16* __restrict__ Bth, const _Float16* __restrict__ Btl,
                const _Float16* __restrict__ TCh, const _Float16* __restrict__ TCl,
                float* __restrict__ out)
{
    __shared__ f32x4 part[2][3][64];
    const int lane = threadIdx.x & 63;
    const int w = threadIdx.x >> 6;
    const int u = w >> 1, kh = w & 1;
    const int bsw = swz8(blockIdx.x, 2048);
    const int unit = bsw * 2 + u;                         // 0..4095
    const int mt = unit >> 4, nt = unit & 15;
    const int l15 = lane & 15, lhi = lane >> 4;
    const int rowA = mt * 16 + l15;

    f32x4 a0 = {}, a1 = {}, a2 = {};
    #pragma unroll
    for (int i = 0; i < 5; ++i) {
        if (kh && i == 4) break;
        const int ks = kh * 5 + i;
        const int ao = rowA * 288 + ks * 32 + lhi * 8;
        half8 Ah = *(const half8*)(Bth + ao);
        half8 Al = *(const half8*)(Btl + ao);
        const int bo = ((ks * 16 + nt) * 64 + lane) * 8;
        half8 Bh = *(const half8*)(TCh + bo);
        half8 Bl = *(const half8*)(TCl + bo);
        a0 = __builtin_amdgcn_mfma_f32_16x16x32_f16(Ah, Bh, a0, 0, 0, 0);
        a1 = __builtin_amdgcn_mfma_f32_16x16x32_f16(Ah, Bl, a1, 0, 0, 0);
        a2 = __builtin_amdgcn_mfma_f32_16x16x32_f16(Al, Bh, a2, 0, 0, 0);
    }
    if (kh) {
        part[u][0][lane] = a0; part[u][1][lane] = a1; part[u][2][lane] = a2;
    }
    __syncthreads();
    if (kh) return;
    a0 += part[u][0][lane]; a1 += part[u][1][lane]; a2 += part[u][2][lane];

    const int rowD = mt * 16 + lhi * 4;
    const int x = nt * 16 + l15;
    #pragma unroll
    for (int r = 0; r < 4; ++r)
        out[(size_t)(rowD + r) * 256 + x] = a0[r] + a1[r] + a2[r];
}

// ---------------------------------------------------------------------------
extern "C" void kernel_launch(void* const* d_in, const int* in_sizes, int n_in,
                              void* d_out, int out_size, void* d_ws, size_t ws_size,
                              hipStream_t stream)
{
    const float* z    = (const float*)d_in[0];
    const float* w1   = (const float*)d_in[1];
    const float* b1   = (const float*)d_in[2];
    const float* w2   = (const float*)d_in[3];
    const float* b2   = (const float*)d_in[4];
    const float* cosw = (const float*)d_in[5];
    const float* wf   = (const float*)d_in[6];
    float* out = (float*)d_out;

    char* p = (char*)d_ws;
    auto take = [&](size_t bytes) {
        char* r = p; p += (bytes + 255) & ~(size_t)255; return r;
    };
    _Float16* g2h = (_Float16*)take(4096 * 256 * 2);
    _Float16* g2l = (_Float16*)take(4096 * 256 * 2);
    _Float16* Zth = (_Float16*)take(2064 * 512 * 2);
    _Float16* Ztl = (_Float16*)take(2064 * 512 * 2);
    _Float16* Ph  = (_Float16*)take(2064 * 512 * 2);
    _Float16* Pl  = (_Float16*)take(2064 * 512 * 2);
    _Float16* Bth = (_Float16*)take(4096 * 288 * 2);
    _Float16* Btl = (_Float16*)take(4096 * 288 * 2);
    _Float16* TAh = (_Float16*)take(69632 * 2);
    _Float16* TAl = (_Float16*)take(69632 * 2);
    _Float16* G1h = (_Float16*)take(131072 * 2);
    _Float16* G1l = (_Float16*)take(131072 * 2);
    _Float16* G3h = (_Float16*)take(131072 * 2);
    _Float16* G3l = (_Float16*)take(131072 * 2);
    _Float16* TCh = (_Float16*)take(73728 * 2);
    _Float16* TCl = (_Float16*)take(73728 * 2);
    _Float16* w1pk  = (_Float16*)take(1024 * 2);
    _Float16* w2lin = (_Float16*)take(9216 * 2);

    prep<<<137, 256, 0, stream>>>(w1, w2, w1pk, w2lin, TAh, TAl,
                                  G1h, G1l, G3h, G3l, TCh, TCl);
    fused_features<<<dim3(16, 16, NS), 256, 0, stream>>>(z, w1pk, b1, w2lin, b2,
                                                         cosw, g2h, g2l);
    fft_rows<<<2176, 256, 0, stream>>>(g2h, g2l, TAh, TAl, Zth, Ztl);
    fft_cols_mul<<<1032, 256, 0, stream>>>(Zth, Ztl, G1h, G1l, wf, Ph, Pl);
    fft_cols_inv<<<1032, 256, 0, stream>>>(Ph, Pl, G3h, G3l, Bth, Btl);
    irfft_rows<<<2048, 256, 0, stream>>>(Bth, Btl, TCh, TCl, out);
}

// Round 11
// 103.873 us; speedup vs baseline: 1.3373x; 1.3373x over previous
//
#include <hip/hip_runtime.h>
#include <math.h>

#define NS   16
#define CIN  3
#define CF   32
#define CROP 256
#define KH   129

typedef _Float16 half8  __attribute__((ext_vector_type(8)));
typedef _Float16 half4v __attribute__((ext_vector_type(4)));
typedef _Float16 half2v __attribute__((ext_vector_type(2)));
typedef float    f32x4  __attribute__((ext_vector_type(4)));
typedef unsigned int u32x4 __attribute__((ext_vector_type(4)));

// exact negation of 8 packed f16 (sign-bit xor); split planes negate exactly
__device__ __forceinline__ half8 neg8(half8 v) {
    u32x4 u = __builtin_bit_cast(u32x4, v);
    u ^= (u32x4){0x80008000u, 0x80008000u, 0x80008000u, 0x80008000u};
    return __builtin_bit_cast(half8, u);
}

// bijective XCD-chunked swizzle (m204)
__device__ __forceinline__ int swz8(int b, int nb) {
    int q = nb >> 3, r = nb & 7;
    int x = b & 7, o = b >> 3;
    return (x < r ? x * (q + 1) : r * (q + 1) + (x - r) * q) + o;
}

// ---------------- LDS layout for fused_features (bytes) -------------------
#define X_OFF 0
#define Z_OFF 21504
#define LDS_BYTES 23904

__device__ __forceinline__ int xaddr(int q, int s) {
    return X_OFF + (q << 6) + ((s ^ ((q >> 1) & 3)) << 4);
}

// channel permutation: row position p <- channel c.
__device__ __forceinline__ int pi_of(int co) {
    int h = co >> 3, j = co & 7;
    return (j < 4) ? (h * 4 + j) : (16 + h * 4 + j - 4);
}
__device__ __forceinline__ int cinv_of(int p) {
    int h = (p & 15) >> 2;
    int j = (p & 3) + ((p >= 16) ? 4 : 0);
    return h * 8 + j;
}

__device__ __forceinline__ void split_pair(float v0, float v1,
                                           half2v* hp, half2v* lp) {
    _Float16 h0 = (_Float16)v0, h1 = (_Float16)v1;
    *hp = (half2v){h0, h1};
    *lp = (half2v){(_Float16)(v0 - (float)h0), (_Float16)(v1 - (float)h1)};
}

// ---------------------------------------------------------------------------
// prep: twiddle tables via 256-entry LDS cos/sin lookup, pair-packed stores.
// 1024 pairs/block. blocks: [0,34) TA | [34,98) G1,G3 | [98,134) TC | [134,137) w
// ---------------------------------------------------------------------------
__global__ __launch_bounds__(256)
void prep(const float* __restrict__ w1, const float* __restrict__ w2,
          _Float16* __restrict__ w1pk, _Float16* __restrict__ w2lin,
          _Float16* __restrict__ TAh, _Float16* __restrict__ TAl,
          _Float16* __restrict__ G1h, _Float16* __restrict__ G1l,
          _Float16* __restrict__ G3h, _Float16* __restrict__ G3l,
          _Float16* __restrict__ TCh, _Float16* __restrict__ TCl)
{
    const int bid = blockIdx.x, tid = threadIdx.x;

    if (bid >= 134) {             // ---- weight prepack (permuted rows) ----
        int base = (bid - 134) * 4096;
        #pragma unroll
        for (int i = 0; i < 16; ++i) {
            int e = base + tid + i * 256;
            if (e < 9216) {       // w2[co][ci][k9] -> w2lin[k9][pi(co)][ci]
                int co = e / 288;
                int r  = e - co * 288;
                int ci = r / 9, k9 = r - ci * 9;
                w2lin[(k9 * 32 + pi_of(co)) * 32 + ci] = (_Float16)w2[e];
            } else if (e < 9344) {
                int t = e - 9216;             // cg*64 + lane
                int lane = t & 63;
                int p = (t >> 6) * 16 + (lane & 15);
                int c = cinv_of(p);
                #pragma unroll
                for (int j = 0; j < 8; ++j) {
                    int k = ((lane >> 4) << 3) + j;
                    w1pk[t * 8 + j] = (k < 27) ? (_Float16)w1[c * 27 + k]
                                               : (_Float16)0.f;
                }
            }
        }
        return;
    }

    __shared__ float cs[256], sn[256];
    {
        float s, c;
        sincosf(0.02454369260617025967f * (float)tid, &s, &c);  // 2*pi/256
        cs[tid] = c; sn[tid] = s;
    }
    __syncthreads();

    // pair index p: elem e = 2p; j0 = (p&3)*2, lane = (p>>2)&63, q = p>>8
    if (bid < 34) {               // ---- TA: 34816 pairs, 1024/block ----
        int base = bid * 1024 + tid;
        #pragma unroll
        for (int i = 0; i < 4; ++i) {
            int p = base + i * 256;
            int j0 = (p & 3) * 2, lane = (p >> 2) & 63, q = p >> 8;
            int nt = q % 17, ks = q / 17;
            int x0 = ks * 32 + ((lane >> 4) << 3) + j0;
            int c = nt * 16 + (lane & 15);
            float v0 = 0.f, v1 = 0.f;
            if (c <= 128) {
                v0 =  cs[(x0 * c) & 255];
                v1 =  cs[((x0 + 1) * c) & 255];
            } else if (c >= 136 && c <= 264) {
                int cc = c - 136;
                v0 = -sn[(x0 * cc) & 255];
                v1 = -sn[((x0 + 1) * cc) & 255];
            }
            half2v hv, lv; split_pair(v0, v1, &hv, &lv);
            ((half2v*)TAh)[p] = hv; ((half2v*)TAl)[p] = lv;
        }
    } else if (bid < 98) {        // ---- G1,G3: 65536 pairs ----
        int base = (bid - 34) * 1024 + tid;
        #pragma unroll
        for (int i = 0; i < 4; ++i) {
            int p = base + i * 256;
            int j0 = (p & 3) * 2, lane = (p >> 2) & 63, q = p >> 8;
            int nt = q & 15, ks = q >> 4;
            int kk0 = ks * 32 + ((lane >> 4) << 3) + j0;
            int m  = nt * 16 + (lane & 15);
            int part = kk0 >> 8;                    // uniform for the pair
            int y0 = kk0 & 255;
            int i0 = (y0 * m) & 255, i1 = ((y0 + 1) * m) & 255;
            float cv0 = cs[i0], s0 = sn[i0], cv1 = cs[i1], s1 = sn[i1];
            half2v hv, lv;
            float a0 = part ? s0 : cv0,  a1 = part ? s1 : cv1;          // G1
            split_pair(a0, a1, &hv, &lv);
            ((half2v*)G1h)[p] = hv; ((half2v*)G1l)[p] = lv;
            a0 = (part ? -s0 : cv0) * (1.f/256.f);                      // G3
            a1 = (part ? -s1 : cv1) * (1.f/256.f);
            split_pair(a0, a1, &hv, &lv);
            ((half2v*)G3h)[p] = hv; ((half2v*)G3l)[p] = lv;
        }
    } else {                      // ---- TC: 36864 pairs ----
        int base = (bid - 98) * 1024 + tid;
        #pragma unroll
        for (int i = 0; i < 4; ++i) {
            int p = base + i * 256;
            int j0 = (p & 3) * 2, lane = (p >> 2) & 63, q = p >> 8;
            int nt = q & 15, ks = q >> 4;
            int kk0 = ks * 32 + ((lane >> 4) << 3) + j0;
            int x  = nt * 16 + (lane & 15);
            int part = (kk0 >= 144) ? 1 : 0;        // pair never straddles
            int k0 = kk0 - part * 144;
            float v0 = 0.f, v1 = 0.f;
            if (k0 <= 128) {
                float w0 = (k0 == 0 || k0 == 128) ? 1.f : 2.f;
                int ii = (k0 * x) & 255;
                v0 = (part ? -w0 * sn[ii] : w0 * cs[ii]) * (1.f/256.f);
            }
            int k1 = k0 + 1;
            if (k1 <= 128) {
                float w1w = (k1 == 0 || k1 == 128) ? 1.f : 2.f;
                int ii = (k1 * x) & 255;
                v1 = (part ? -w1w * sn[ii] : w1w * cs[ii]) * (1.f/256.f);
            }
            half2v hv, lv; split_pair(v0, v1, &hv, &lv);
            ((half2v*)TCh)[p] = hv; ((half2v*)TCl)[p] = lv;
        }
    }
}

// ---------------------------------------------------------------------------
// Kernel 1: fused conv1+ReLU -> conv2 -> LRN -> *cos_window -> channel sum
// (round-5/8 measured-best: launch_bounds (256,5), VGPR 48, NO spill)
// ---------------------------------------------------------------------------
__global__ __launch_bounds__(256, 5)
void fused_features(const float* __restrict__ z,
                    const _Float16* __restrict__ w1pk,
                    const float* __restrict__ b1,
                    const _Float16* __restrict__ w2lin,
                    const float* __restrict__ b2,
                    const float* __restrict__ cosw,
                    _Float16* __restrict__ g2h, _Float16* __restrict__ g2l)
{
    __shared__ __align__(16) unsigned char smem[LDS_BYTES];
    _Float16* ztile = (_Float16*)(smem + Z_OFF);

    const int tid  = threadIdx.x;
    const int lane = tid & 63;
    const int wv   = tid >> 6;
    const int l15  = lane & 15;
    const int lhi  = lane >> 4;

    const int n  = blockIdx.z;
    const int bx = blockIdx.x, by = blockIdx.y;
    const int fy0 = by * 16 - 1;
    const int fx0 = bx * 16 - 1;

    const int zy0 = by * 16 - 2;
    const int zx0 = bx * 16 - 2;
    for (int idx = tid; idx < CIN * 400; idx += 256) {
        int ci = idx / 400;
        int r  = idx - ci * 400;
        int yy = r / 20, xx = r - yy * 20;
        int gy = zy0 + yy, gx = zx0 + xx;
        float v = 0.0f;
        if ((unsigned)gy < CROP && (unsigned)gx < CROP)
            v = z[((n * CIN + ci) * CROP + gy) * CROP + gx];
        ztile[idx] = (_Float16)v;
    }

    half8 w1f0 = *(const half8*)(w1pk + lane * 8);
    half8 w1f1 = *(const half8*)(w1pk + 512 + lane * 8);
    float bias1v[2][4], bias2v[2][4];
    #pragma unroll
    for (int cg = 0; cg < 2; ++cg)
        #pragma unroll
        for (int r = 0; r < 4; ++r) {
            bias1v[cg][r] = b1[8 * lhi + 4 * cg + r];
            bias2v[cg][r] = b2[8 * lhi + 4 * cg + r];
        }

    int offs[8];
    #pragma unroll
    for (int j = 0; j < 8; ++j) {
        int k = lhi * 8 + j;
        int ci = k / 9, rr = k - ci * 9;
        int ky = rr / 3, kx = rr - ky * 3;
        offs[j] = (k < 27) ? (ci * 400 + ky * 20 + kx) : 0;
    }
    __syncthreads();

    const f32x4 zero4 = {0.f, 0.f, 0.f, 0.f};
    for (int t = wv; t < 21; t += 4) {
        int qp = t * 16 + l15;
        int qpc = qp < 324 ? qp : 323;
        int y = qpc / 18, x = qpc - y * 18;
        const _Float16* zb = ztile + y * 20 + x;
        half8 bfrag;
        #pragma unroll
        for (int j = 0; j < 8; ++j) bfrag[j] = zb[offs[j]];
        f32x4 d0 = __builtin_amdgcn_mfma_f32_16x16x32_f16(w1f0, bfrag, zero4, 0, 0, 0);
        f32x4 d1 = __builtin_amdgcn_mfma_f32_16x16x32_f16(w1f1, bfrag, zero4, 0, 0, 0);
        int gy = fy0 + y, gx = fx0 + x;
        bool ok = ((unsigned)gy < CROP) && ((unsigned)gx < CROP) && (qp < 324);
        half8 o8;
        #pragma unroll
        for (int r = 0; r < 4; ++r) {
            float v0 = ok ? fmaxf(d0[r] + bias1v[0][r], 0.f) : 0.f;
            float v1 = ok ? fmaxf(d1[r] + bias1v[1][r], 0.f) : 0.f;
            o8[r]     = (_Float16)v0;
            o8[4 + r] = (_Float16)v1;
        }
        *(half8*)(smem + xaddr(qp, lhi)) = o8;
    }
    __syncthreads();

    f32x4 acc[4][2];
    #pragma unroll
    for (int tt = 0; tt < 4; ++tt)
        #pragma unroll
        for (int cg = 0; cg < 2; ++cg)
            #pragma unroll
            for (int r = 0; r < 4; ++r)
                acc[tt][cg][r] = bias2v[cg][r];

    #pragma unroll
    for (int k9 = 0; k9 < 9; ++k9) {
        const int ky = k9 / 3, kx = k9 - 3 * ky;
        half8 af0 = *(const half8*)(w2lin + (k9 * 32 + l15)      * 32 + lhi * 8);
        half8 af1 = *(const half8*)(w2lin + (k9 * 32 + l15 + 16) * 32 + lhi * 8);
        #pragma unroll
        for (int tt = 0; tt < 4; ++tt) {
            int q = (wv * 4 + tt + ky) * 18 + l15 + kx;
            half8 bf = *(const half8*)(smem + xaddr(q, lhi));
            acc[tt][0] = __builtin_amdgcn_mfma_f32_16x16x32_f16(af0, bf, acc[tt][0], 0, 0, 0);
            acc[tt][1] = __builtin_amdgcn_mfma_f32_16x16x32_f16(af1, bf, acc[tt][1], 0, 0, 0);
        }
    }

    const bool bot = (lhi == 0), top = (lhi == 3);
    #pragma unroll
    for (int tt = 0; tt < 4; ++tt) {
        float aA0 = acc[tt][0][0], aA1 = acc[tt][0][1],
              aA2 = acc[tt][0][2], aA3 = acc[tt][0][3];
        float aB0 = acc[tt][1][0], aB1 = acc[tt][1][1],
              aB2 = acc[tt][1][2], aB3 = acc[tt][1][3];
        float sA0 = aA0 * aA0, sA1 = aA1 * aA1, sA2 = aA2 * aA2, sA3 = aA3 * aA3;
        float sB0 = aB0 * aB0, sB1 = aB1 * aB1, sB2 = aB2 * aB2, sB3 = aB3 * aB3;
        int up = (lane + 16) & 63, dn = (lane + 48) & 63;
        float em2 = __shfl(sB2, dn); em2 = bot ? 0.f : em2;
        float em1 = __shfl(sB3, dn); em1 = bot ? 0.f : em1;
        float ep8 = __shfl(sA0, up); ep8 = top ? 0.f : ep8;
        float ep9 = __shfl(sA1, up); ep9 = top ? 0.f : ep9;
        float s = 0.f, win = em2 + em1 + sA0 + sA1 + sA2;
        float t2, f;
        t2 = 2e-5f * win; f = fmaf(t2, fmaf(t2, 0.65625f, -0.75f), 1.0f);
        s = fmaf(aA0, f, s);  win += sA3 - em2;
        t2 = 2e-5f * win; f = fmaf(t2, fmaf(t2, 0.65625f, -0.75f), 1.0f);
        s = fmaf(aA1, f, s);  win += sB0 - em1;
        t2 = 2e-5f * win; f = fmaf(t2, fmaf(t2, 0.65625f, -0.75f), 1.0f);
        s = fmaf(aA2, f, s);  win += sB1 - sA0;
        t2 = 2e-5f * win; f = fmaf(t2, fmaf(t2, 0.65625f, -0.75f), 1.0f);
        s = fmaf(aA3, f, s);  win += sB2 - sA1;
        t2 = 2e-5f * win; f = fmaf(t2, fmaf(t2, 0.65625f, -0.75f), 1.0f);
        s = fmaf(aB0, f, s);  win += sB3 - sA2;
        t2 = 2e-5f * win; f = fmaf(t2, fmaf(t2, 0.65625f, -0.75f), 1.0f);
        s = fmaf(aB1, f, s);  win += ep8 - sA3;
        t2 = 2e-5f * win; f = fmaf(t2, fmaf(t2, 0.65625f, -0.75f), 1.0f);
        s = fmaf(aB2, f, s);  win += ep9 - sB0;
        t2 = 2e-5f * win; f = fmaf(t2, fmaf(t2, 0.65625f, -0.75f), 1.0f);
        s = fmaf(aB3, f, s);
        s += __shfl_xor(s, 16);
        s += __shfl_xor(s, 32);
        if (lhi == 0) {
            int gy = by * 16 + wv * 4 + tt, gx = bx * 16 + l15;
            float val = s * cosw[gy * CROP + gx];
            _Float16 h = (_Float16)val;
            int o = (n * CROP + gy) * CROP + gx;
            g2h[o] = h;
            g2l[o] = (_Float16)(val - (float)h);
        }
    }
}

// ---------------------------------------------------------------------------
// Stage A: row rfft. SPLIT-K: 2 waves per unit (kh=0: ks0..3, kh=1: ks4..7),
// LDS partial exchange. 2176 blocks, XCD-chunked.
// ---------------------------------------------------------------------------
__global__ __launch_bounds__(256, 4)
void fft_rows(const _Float16* __restrict__ g2h, const _Float16* __restrict__ g2l,
              const _Float16* __restrict__ TAh, const _Float16* __restrict__ TAl,
              _Float16* __restrict__ Zth, _Float16* __restrict__ Ztl)
{
    __shared__ f32x4 part[2][3][64];
    const int lane = threadIdx.x & 63;
    const int w = threadIdx.x >> 6;
    const int u = w >> 1, kh = w & 1;
    const int bsw = swz8(blockIdx.x, 2176);
    const int unit = bsw * 2 + u;                         // 0..4351
    const int mt = unit / 17, nt = unit - mt * 17;
    const int l15 = lane & 15, lhi = lane >> 4;
    const int rowA = mt * 16 + l15;

    f32x4 a0 = {}, a1 = {}, a2 = {};
    #pragma unroll
    for (int i = 0; i < 4; ++i) {
        const int ks = kh * 4 + i;
        const int ao = rowA * 256 + ks * 32 + lhi * 8;
        half8 Ah = *(const half8*)(g2h + ao);
        half8 Al = *(const half8*)(g2l + ao);
        const int bo = ((ks * 17 + nt) * 64 + lane) * 8;
        half8 Bh = *(const half8*)(TAh + bo);
        half8 Bl = *(const half8*)(TAl + bo);
        a0 = __builtin_amdgcn_mfma_f32_16x16x32_f16(Ah, Bh, a0, 0, 0, 0);
        a1 = __builtin_amdgcn_mfma_f32_16x16x32_f16(Ah, Bl, a1, 0, 0, 0);
        a2 = __builtin_amdgcn_mfma_f32_16x16x32_f16(Al, Bh, a2, 0, 0, 0);
    }
    if (kh) {
        part[u][0][lane] = a0; part[u][1][lane] = a1; part[u][2][lane] = a2;
    }
    __syncthreads();
    if (kh) return;
    a0 += part[u][0][lane]; a1 += part[u][1][lane]; a2 += part[u][2][lane];

    f32x4 acc;
    #pragma unroll
    for (int r = 0; r < 4; ++r) acc[r] = a0[r] + a1[r] + a2[r];

    const int rowD = mt * 16 + lhi * 4;
    const int n = rowD >> 8, y = rowD & 255;
    int c = nt * 16 + l15;
    int row_k = -1, koff = 0;
    if (c <= 128)                  { row_k = c;       koff = 0;   }
    else if (c >= 136 && c <= 264) { row_k = c - 136; koff = 256; }
    if (row_k >= 0) {
        half4v hv, lv;
        #pragma unroll
        for (int r = 0; r < 4; ++r) {
            float v = acc[r];
            _Float16 h = (_Float16)v;
            hv[r] = h; lv[r] = (_Float16)(v - (float)h);
        }
        size_t o = (size_t)(n * 129 + row_k) * 512 + koff + y;
        *(half4v*)(Zth + o) = hv;
        *(half4v*)(Ztl + o) = lv;
    }
}

// ---------------------------------------------------------------------------
// Stage B1: col fft + *conj(wf[0,1]). SPLIT-K + ks-mirror. 1032 blocks.
// ---------------------------------------------------------------------------
__global__ __launch_bounds__(256, 4)
void fft_cols_mul(const _Float16* __restrict__ Zth, const _Float16* __restrict__ Ztl,
                  const _Float16* __restrict__ G1h, const _Float16* __restrict__ G1l,
                  const float* __restrict__ wf,
                  _Float16* __restrict__ Ph, _Float16* __restrict__ Pl)
{
    __shared__ f32x4 part[2][6][64];
    const int lane = threadIdx.x & 63;
    const int w = threadIdx.x >> 6;
    const int u = w >> 1, kh = w & 1;
    const int bsw = swz8(blockIdx.x, 1032);
    const int unit = bsw * 2 + u;                         // 0..2063
    const int mt = unit >> 4, nt = unit & 15;             // mt: 0..128
    const int l15 = lane & 15, lhi = lane >> 4;
    const int rowA = mt * 16 + l15;

    f32x4 r0 = {}, r1 = {}, r2 = {}, i0 = {}, i1 = {}, i2 = {};
    #pragma unroll
    for (int i = 0; i < 4; ++i) {
        const int ks = kh * 4 + i;
        const int ao0 = rowA * 512 + ks * 32 + lhi * 8;
        half8 Ah0 = *(const half8*)(Zth + ao0);
        half8 Al0 = *(const half8*)(Ztl + ao0);
        half8 Ah1 = *(const half8*)(Zth + ao0 + 256);
        half8 Al1 = *(const half8*)(Ztl + ao0 + 256);
        const int bo0 = ((ks * 16 + nt) * 64 + lane) * 8;
        half8 B0h = *(const half8*)(G1h + bo0);            // G1[ks]
        half8 B0l = *(const half8*)(G1l + bo0);
        half8 B1h_ = *(const half8*)(G1h + bo0 + 65536);   // G1[ks+8]
        half8 B1l_ = *(const half8*)(G1l + bo0 + 65536);
        half8 nB1h = neg8(B1h_), nB1l = neg8(B1l_);        // G2[ks] = -G1[ks+8]
        r0 = __builtin_amdgcn_mfma_f32_16x16x32_f16(Ah0, B0h,  r0, 0, 0, 0);
        r1 = __builtin_amdgcn_mfma_f32_16x16x32_f16(Ah0, B0l,  r1, 0, 0, 0);
        r2 = __builtin_amdgcn_mfma_f32_16x16x32_f16(Al0, B0h,  r2, 0, 0, 0);
        r0 = __builtin_amdgcn_mfma_f32_16x16x32_f16(Ah1, B1h_, r0, 0, 0, 0);
        r1 = __builtin_amdgcn_mfma_f32_16x16x32_f16(Ah1, B1l_, r1, 0, 0, 0);
        r2 = __builtin_amdgcn_mfma_f32_16x16x32_f16(Al1, B1h_, r2, 0, 0, 0);
        i0 = __builtin_amdgcn_mfma_f32_16x16x32_f16(Ah0, nB1h, i0, 0, 0, 0);
        i1 = __builtin_amdgcn_mfma_f32_16x16x32_f16(Ah0, nB1l, i1, 0, 0, 0);
        i2 = __builtin_amdgcn_mfma_f32_16x16x32_f16(Al0, nB1h, i2, 0, 0, 0);
        i0 = __builtin_amdgcn_mfma_f32_16x16x32_f16(Ah1, B0h,  i0, 0, 0, 0);
        i1 = __builtin_amdgcn_mfma_f32_16x16x32_f16(Ah1, B0l,  i1, 0, 0, 0);
        i2 = __builtin_amdgcn_mfma_f32_16x16x32_f16(Al1, B0h,  i2, 0, 0, 0);
    }
    if (kh) {
        part[u][0][lane] = r0; part[u][1][lane] = r1; part[u][2][lane] = r2;
        part[u][3][lane] = i0; part[u][4][lane] = i1; part[u][5][lane] = i2;
    }
    __syncthreads();
    if (kh) return;
    r0 += part[u][0][lane]; r1 += part[u][1][lane]; r2 += part[u][2][lane];
    i0 += part[u][3][lane]; i1 += part[u][4][lane]; i2 += part[u][5][lane];

    const int rowP0 = mt * 16 + lhi * 4;
    const int m = nt * 16 + l15;
    const float* wf1 = wf + 256 * 129 * 2;
    int n_ = rowP0 / 129;
    int k_ = rowP0 - n_ * 129;
    #pragma unroll
    for (int r = 0; r < 4; ++r) {
        float wr = wf1[(m * 129 + k_) * 2 + 0];
        float wi = wf1[(m * 129 + k_) * 2 + 1];
        float fr = r0[r] + r1[r] + r2[r];
        float fi = i0[r] + i1[r] + i2[r];
        float pr = wr * fr + wi * fi;
        float pi = wr * fi - wi * fr;
        size_t o = (size_t)(rowP0 + r) * 512 + m;
        _Float16 h;
        h = (_Float16)pr; Ph[o] = h;       Pl[o] = (_Float16)(pr - (float)h);
        h = (_Float16)pi; Ph[o + 256] = h; Pl[o + 256] = (_Float16)(pi - (float)h);
        if (++k_ == 129) { k_ = 0; ++n_; }
    }
}

// ---------------------------------------------------------------------------
// Stage B2: col ifft (1/256). SPLIT-K + R/I merged + ks-mirror. 1032 blocks.
// ---------------------------------------------------------------------------
__global__ __launch_bounds__(256, 4)
void fft_cols_inv(const _Float16* __restrict__ Ph, const _Float16* __restrict__ Pl,
                  const _Float16* __restrict__ G3h, const _Float16* __restrict__ G3l,
                  _Float16* __restrict__ Bth, _Float16* __restrict__ Btl)
{
    __shared__ f32x4 part[2][6][64];
    const int lane = threadIdx.x & 63;
    const int w = threadIdx.x >> 6;
    const int u = w >> 1, kh = w & 1;
    const int bsw = swz8(blockIdx.x, 1032);
    const int unit = bsw * 2 + u;                         // 0..2063
    const int mt = unit >> 4, nt = unit & 15;
    const int l15 = lane & 15, lhi = lane >> 4;
    const int rowA = mt * 16 + l15;

    f32x4 r0 = {}, r1 = {}, r2 = {}, i0 = {}, i1 = {}, i2 = {};
    #pragma unroll
    for (int i = 0; i < 4; ++i) {
        const int ks = kh * 4 + i;
        const int ao0 = rowA * 512 + ks * 32 + lhi * 8;
        half8 Ah0 = *(const half8*)(Ph + ao0);
        half8 Al0 = *(const half8*)(Pl + ao0);
        half8 Ah1 = *(const half8*)(Ph + ao0 + 256);
        half8 Al1 = *(const half8*)(Pl + ao0 + 256);
        const int bo0 = ((ks * 16 + nt) * 64 + lane) * 8;
        half8 B0h = *(const half8*)(G3h + bo0);            // G3[ks]
        half8 B0l = *(const half8*)(G3l + bo0);
        half8 B1h_ = *(const half8*)(G3h + bo0 + 65536);   // G3[ks+8]
        half8 B1l_ = *(const half8*)(G3l + bo0 + 65536);
        half8 nB1h = neg8(B1h_), nB1l = neg8(B1l_);        // G4[ks] = -G3[ks+8]
        r0 = __builtin_amdgcn_mfma_f32_16x16x32_f16(Ah0, B0h,  r0, 0, 0, 0);
        r1 = __builtin_amdgcn_mfma_f32_16x16x32_f16(Ah0, B0l,  r1, 0, 0, 0);
        r2 = __builtin_amdgcn_mfma_f32_16x16x32_f16(Al0, B0h,  r2, 0, 0, 0);
        r0 = __builtin_amdgcn_mfma_f32_16x16x32_f16(Ah1, B1h_, r0, 0, 0, 0);
        r1 = __builtin_amdgcn_mfma_f32_16x16x32_f16(Ah1, B1l_, r1, 0, 0, 0);
        r2 = __builtin_amdgcn_mfma_f32_16x16x32_f16(Al1, B1h_, r2, 0, 0, 0);
        i0 = __builtin_amdgcn_mfma_f32_16x16x32_f16(Ah0, nB1h, i0, 0, 0, 0);
        i1 = __builtin_amdgcn_mfma_f32_16x16x32_f16(Ah0, nB1l, i1, 0, 0, 0);
        i2 = __builtin_amdgcn_mfma_f32_16x16x32_f16(Al0, nB1h, i2, 0, 0, 0);
        i0 = __builtin_amdgcn_mfma_f32_16x16x32_f16(Ah1, B0h,  i0, 0, 0, 0);
        i1 = __builtin_amdgcn_mfma_f32_16x16x32_f16(Ah1, B0l,  i1, 0, 0, 0);
        i2 = __builtin_amdgcn_mfma_f32_16x16x32_f16(Al1, B0h,  i2, 0, 0, 0);
    }
    if (kh) {
        part[u][0][lane] = r0; part[u][1][lane] = r1; part[u][2][lane] = r2;
        part[u][3][lane] = i0; part[u][4][lane] = i1; part[u][5][lane] = i2;
    }
    __syncthreads();
    if (kh) return;
    r0 += part[u][0][lane]; r1 += part[u][1][lane]; r2 += part[u][2][lane];
    i0 += part[u][3][lane]; i1 += part[u][4][lane]; i2 += part[u][5][lane];

    const int rowP0 = mt * 16 + lhi * 4;
    const int y = nt * 16 + l15;
    int n_ = rowP0 / 129;
    int k_ = rowP0 - n_ * 129;
    #pragma unroll
    for (int r = 0; r < 4; ++r) {
        size_t base = (size_t)(n_ * 256 + y) * 288 + k_;
        float v = r0[r] + r1[r] + r2[r];
        _Float16 h = (_Float16)v;
        Bth[base] = h;  Btl[base] = (_Float16)(v - (float)h);
        float v2 = i0[r] + i1[r] + i2[r];
        _Float16 h2 = (_Float16)v2;
        Bth[base + 144] = h2;  Btl[base + 144] = (_Float16)(v2 - (float)h2);
        if (++k_ == 129) { k_ = 0; ++n_; }
    }
}

// ---------------------------------------------------------------------------
// Stage C: row irfft (1/256). SPLIT-K (kh0: ks0..4, kh1: ks5..8). 2048 blocks.
// ---------------------------------------------------------------------------
__global__ __launch_bounds__(256, 4)
void irfft_rows(const _Float16* __restrict__ Bth, const _Float16* __restrict__ Btl,
                const _Float16* __restrict__ TCh, const _Float16* __restrict__ TCl,
                float* __restrict__ out)
{
    __shared__ f32x4 part[2][3][64];
    const int lane = threadIdx.x & 63;
    const int w = threadIdx.x >> 6;
    const int u = w >> 1, kh = w & 1;
    const int bsw = swz8(blockIdx.x, 2048);
    const int unit = bsw * 2 + u;                         // 0..4095
    const int mt = unit >> 4, nt = unit & 15;
    const int l15 = lane & 15, lhi = lane >> 4;
    const int rowA = mt * 16 + l15;

    f32x4 a0 = {}, a1 = {}, a2 = {};
    #pragma unroll
    for (int i = 0; i < 5; ++i) {
        if (kh && i == 4) break;
        const int ks = kh * 5 + i;
        const int ao = rowA * 288 + ks * 32 + lhi * 8;
        half8 Ah = *(const half8*)(Bth + ao);
        half8 Al = *(const half8*)(Btl + ao);
        const int bo = ((ks * 16 + nt) * 64 + lane) * 8;
        half8 Bh = *(const half8*)(TCh + bo);
        half8 Bl = *(const half8*)(TCl + bo);
        a0 = __builtin_amdgcn_mfma_f32_16x16x32_f16(Ah, Bh, a0, 0, 0, 0);
        a1 = __builtin_amdgcn_mfma_f32_16x16x32_f16(Ah, Bl, a1, 0, 0, 0);
        a2 = __builtin_amdgcn_mfma_f32_16x16x32_f16(Al, Bh, a2, 0, 0, 0);
    }
    if (kh) {
        part[u][0][lane] = a0; part[u][1][lane] = a1; part[u][2][lane] = a2;
    }
    __syncthreads();
    if (kh) return;
    a0 += part[u][0][lane]; a1 += part[u][1][lane]; a2 += part[u][2][lane];

    const int rowD = mt * 16 + lhi * 4;
    const int x = nt * 16 + l15;
    #pragma unroll
    for (int r = 0; r < 4; ++r)
        out[(size_t)(rowD + r) * 256 + x] = a0[r] + a1[r] + a2[r];
}

// ---------------------------------------------------------------------------
extern "C" void kernel_launch(void* const* d_in, const int* in_sizes, int n_in,
                              void* d_out, int out_size, void* d_ws, size_t ws_size,
                              hipStream_t stream)
{
    const float* z    = (const float*)d_in[0];
    const float* w1   = (const float*)d_in[1];
    const float* b1   = (const float*)d_in[2];
    const float* w2   = (const float*)d_in[3];
    const float* b2   = (const float*)d_in[4];
    const float* cosw = (const float*)d_in[5];
    const float* wf   = (const float*)d_in[6];
    float* out = (float*)d_out;

    char* p = (char*)d_ws;
    auto take = [&](size_t bytes) {
        char* r = p; p += (bytes + 255) & ~(size_t)255; return r;
    };
    _Float16* g2h = (_Float16*)take(4096 * 256 * 2);
    _Float16* g2l = (_Float16*)take(4096 * 256 * 2);
    _Float16* Zth = (_Float16*)take(2064 * 512 * 2);
    _Float16* Ztl = (_Float16*)take(2064 * 512 * 2);
    _Float16* Ph  = (_Float16*)take(2064 * 512 * 2);
    _Float16* Pl  = (_Float16*)take(2064 * 512 * 2);
    _Float16* Bth = (_Float16*)take(4096 * 288 * 2);
    _Float16* Btl = (_Float16*)take(4096 * 288 * 2);
    _Float16* TAh = (_Float16*)take(69632 * 2);
    _Float16* TAl = (_Float16*)take(69632 * 2);
    _Float16* G1h = (_Float16*)take(131072 * 2);
    _Float16* G1l = (_Float16*)take(131072 * 2);
    _Float16* G3h = (_Float16*)take(131072 * 2);
    _Float16* G3l = (_Float16*)take(131072 * 2);
    _Float16* TCh = (_Float16*)take(73728 * 2);
    _Float16* TCl = (_Float16*)take(73728 * 2);
    _Float16* w1pk  = (_Float16*)take(1024 * 2);
    _Float16* w2lin = (_Float16*)take(9216 * 2);

    prep<<<137, 256, 0, stream>>>(w1, w2, w1pk, w2lin, TAh, TAl,
                                  G1h, G1l, G3h, G3l, TCh, TCl);
    fused_features<<<dim3(16, 16, NS), 256, 0, stream>>>(z, w1pk, b1, w2lin, b2,
                                                         cosw, g2h, g2l);
    fft_rows<<<2176, 256, 0, stream>>>(g2h, g2l, TAh, TAl, Zth, Ztl);
    fft_cols_mul<<<1032, 256, 0, stream>>>(Zth, Ztl, G1h, G1l, wf, Ph, Pl);
    fft_cols_inv<<<1032, 256, 0, stream>>>(Ph, Pl, G3h, G3l, Bth, Btl);
    irfft_rows<<<2048, 256, 0, stream>>>(Bth, Btl, TCh, TCl, out);
}

// Round 12
// 101.233 us; speedup vs baseline: 1.3721x; 1.0261x over previous
//
#include <hip/hip_runtime.h>
#include <math.h>

#define NS   16
#define CIN  3
#define CF   32
#define CROP 256
#define KH   129

typedef _Float16 half8  __attribute__((ext_vector_type(8)));
typedef _Float16 half4v __attribute__((ext_vector_type(4)));
typedef _Float16 half2v __attribute__((ext_vector_type(2)));
typedef float    f32x4  __attribute__((ext_vector_type(4)));
typedef unsigned int u32x4 __attribute__((ext_vector_type(4)));

// exact negation of 8 packed f16 (sign-bit xor); split planes negate exactly
__device__ __forceinline__ half8 neg8(half8 v) {
    u32x4 u = __builtin_bit_cast(u32x4, v);
    u ^= (u32x4){0x80008000u, 0x80008000u, 0x80008000u, 0x80008000u};
    return __builtin_bit_cast(half8, u);
}

// bijective XCD-chunked swizzle (m204)
__device__ __forceinline__ int swz8(int b, int nb) {
    int q = nb >> 3, r = nb & 7;
    int x = b & 7, o = b >> 3;
    return (x < r ? x * (q + 1) : r * (q + 1) + (x - r) * q) + o;
}

// ---------------- LDS layout for fused_features (bytes) -------------------
#define X_OFF 0
#define Z_OFF 21504
#define LDS_BYTES 23904

__device__ __forceinline__ int xaddr(int q, int s) {
    return X_OFF + (q << 6) + ((s ^ ((q >> 1) & 3)) << 4);
}

// channel permutation: row position p <- channel c.
__device__ __forceinline__ int pi_of(int co) {
    int h = co >> 3, j = co & 7;
    return (j < 4) ? (h * 4 + j) : (16 + h * 4 + j - 4);
}
__device__ __forceinline__ int cinv_of(int p) {
    int h = (p & 15) >> 2;
    int j = (p & 3) + ((p >= 16) ? 4 : 0);
    return h * 8 + j;
}

__device__ __forceinline__ void split_pair(float v0, float v1,
                                           half2v* hp, half2v* lp) {
    _Float16 h0 = (_Float16)v0, h1 = (_Float16)v1;
    *hp = (half2v){h0, h1};
    *lp = (half2v){(_Float16)(v0 - (float)h0), (_Float16)(v1 - (float)h1)};
}

// ---------------------------------------------------------------------------
// prep: only what MUST precede fused_features / fft_rows:
//   TA twiddles (fft_rows reads them) + weight prepack (fused reads them).
// G1/G3/TC generation moved into the fft_rows dispatch (consumed only later).
// blocks: [0,34) TA | [34,37) weights
// ---------------------------------------------------------------------------
__global__ __launch_bounds__(256)
void prep(const float* __restrict__ w1, const float* __restrict__ w2,
          _Float16* __restrict__ w1pk, _Float16* __restrict__ w2lin,
          _Float16* __restrict__ TAh, _Float16* __restrict__ TAl)
{
    const int bid = blockIdx.x, tid = threadIdx.x;

    if (bid >= 34) {              // ---- weight prepack (permuted rows) ----
        int base = (bid - 34) * 4096;
        #pragma unroll
        for (int i = 0; i < 16; ++i) {
            int e = base + tid + i * 256;
            if (e < 9216) {       // w2[co][ci][k9] -> w2lin[k9][pi(co)][ci]
                int co = e / 288;
                int r  = e - co * 288;
                int ci = r / 9, k9 = r - ci * 9;
                w2lin[(k9 * 32 + pi_of(co)) * 32 + ci] = (_Float16)w2[e];
            } else if (e < 9344) {
                int t = e - 9216;             // cg*64 + lane
                int lane = t & 63;
                int p = (t >> 6) * 16 + (lane & 15);
                int c = cinv_of(p);
                #pragma unroll
                for (int j = 0; j < 8; ++j) {
                    int k = ((lane >> 4) << 3) + j;
                    w1pk[t * 8 + j] = (k < 27) ? (_Float16)w1[c * 27 + k]
                                               : (_Float16)0.f;
                }
            }
        }
        return;
    }

    __shared__ float cs[256], sn[256];
    {
        float s, c;
        sincosf(0.02454369260617025967f * (float)tid, &s, &c);  // 2*pi/256
        cs[tid] = c; sn[tid] = s;
    }
    __syncthreads();

    // ---- TA: 34816 pairs, 1024/block ----
    int base = bid * 1024 + tid;
    #pragma unroll
    for (int i = 0; i < 4; ++i) {
        int p = base + i * 256;
        int j0 = (p & 3) * 2, lane = (p >> 2) & 63, q = p >> 8;
        int nt = q % 17, ks = q / 17;
        int x0 = ks * 32 + ((lane >> 4) << 3) + j0;
        int c = nt * 16 + (lane & 15);
        float v0 = 0.f, v1 = 0.f;
        if (c <= 128) {
            v0 =  cs[(x0 * c) & 255];
            v1 =  cs[((x0 + 1) * c) & 255];
        } else if (c >= 136 && c <= 264) {
            int cc = c - 136;
            v0 = -sn[(x0 * cc) & 255];
            v1 = -sn[((x0 + 1) * cc) & 255];
        }
        half2v hv, lv; split_pair(v0, v1, &hv, &lv);
        ((half2v*)TAh)[p] = hv; ((half2v*)TAl)[p] = lv;
    }
}

// ---------------------------------------------------------------------------
// Kernel 1: fused conv1+ReLU -> conv2 -> LRN -> *cos_window -> channel sum
// (measured-best: launch_bounds (256,5), VGPR 48, NO spill — unchanged)
// ---------------------------------------------------------------------------
__global__ __launch_bounds__(256, 5)
void fused_features(const float* __restrict__ z,
                    const _Float16* __restrict__ w1pk,
                    const float* __restrict__ b1,
                    const _Float16* __restrict__ w2lin,
                    const float* __restrict__ b2,
                    const float* __restrict__ cosw,
                    _Float16* __restrict__ g2h, _Float16* __restrict__ g2l)
{
    __shared__ __align__(16) unsigned char smem[LDS_BYTES];
    _Float16* ztile = (_Float16*)(smem + Z_OFF);

    const int tid  = threadIdx.x;
    const int lane = tid & 63;
    const int wv   = tid >> 6;
    const int l15  = lane & 15;
    const int lhi  = lane >> 4;

    const int n  = blockIdx.z;
    const int bx = blockIdx.x, by = blockIdx.y;
    const int fy0 = by * 16 - 1;
    const int fx0 = bx * 16 - 1;

    const int zy0 = by * 16 - 2;
    const int zx0 = bx * 16 - 2;
    for (int idx = tid; idx < CIN * 400; idx += 256) {
        int ci = idx / 400;
        int r  = idx - ci * 400;
        int yy = r / 20, xx = r - yy * 20;
        int gy = zy0 + yy, gx = zx0 + xx;
        float v = 0.0f;
        if ((unsigned)gy < CROP && (unsigned)gx < CROP)
            v = z[((n * CIN + ci) * CROP + gy) * CROP + gx];
        ztile[idx] = (_Float16)v;
    }

    half8 w1f0 = *(const half8*)(w1pk + lane * 8);
    half8 w1f1 = *(const half8*)(w1pk + 512 + lane * 8);
    float bias1v[2][4], bias2v[2][4];
    #pragma unroll
    for (int cg = 0; cg < 2; ++cg)
        #pragma unroll
        for (int r = 0; r < 4; ++r) {
            bias1v[cg][r] = b1[8 * lhi + 4 * cg + r];
            bias2v[cg][r] = b2[8 * lhi + 4 * cg + r];
        }

    int offs[8];
    #pragma unroll
    for (int j = 0; j < 8; ++j) {
        int k = lhi * 8 + j;
        int ci = k / 9, rr = k - ci * 9;
        int ky = rr / 3, kx = rr - ky * 3;
        offs[j] = (k < 27) ? (ci * 400 + ky * 20 + kx) : 0;
    }
    __syncthreads();

    const f32x4 zero4 = {0.f, 0.f, 0.f, 0.f};
    for (int t = wv; t < 21; t += 4) {
        int qp = t * 16 + l15;
        int qpc = qp < 324 ? qp : 323;
        int y = qpc / 18, x = qpc - y * 18;
        const _Float16* zb = ztile + y * 20 + x;
        half8 bfrag;
        #pragma unroll
        for (int j = 0; j < 8; ++j) bfrag[j] = zb[offs[j]];
        f32x4 d0 = __builtin_amdgcn_mfma_f32_16x16x32_f16(w1f0, bfrag, zero4, 0, 0, 0);
        f32x4 d1 = __builtin_amdgcn_mfma_f32_16x16x32_f16(w1f1, bfrag, zero4, 0, 0, 0);
        int gy = fy0 + y, gx = fx0 + x;
        bool ok = ((unsigned)gy < CROP) && ((unsigned)gx < CROP) && (qp < 324);
        half8 o8;
        #pragma unroll
        for (int r = 0; r < 4; ++r) {
            float v0 = ok ? fmaxf(d0[r] + bias1v[0][r], 0.f) : 0.f;
            float v1 = ok ? fmaxf(d1[r] + bias1v[1][r], 0.f) : 0.f;
            o8[r]     = (_Float16)v0;
            o8[4 + r] = (_Float16)v1;
        }
        *(half8*)(smem + xaddr(qp, lhi)) = o8;
    }
    __syncthreads();

    f32x4 acc[4][2];
    #pragma unroll
    for (int tt = 0; tt < 4; ++tt)
        #pragma unroll
        for (int cg = 0; cg < 2; ++cg)
            #pragma unroll
            for (int r = 0; r < 4; ++r)
                acc[tt][cg][r] = bias2v[cg][r];

    #pragma unroll
    for (int k9 = 0; k9 < 9; ++k9) {
        const int ky = k9 / 3, kx = k9 - 3 * ky;
        half8 af0 = *(const half8*)(w2lin + (k9 * 32 + l15)      * 32 + lhi * 8);
        half8 af1 = *(const half8*)(w2lin + (k9 * 32 + l15 + 16) * 32 + lhi * 8);
        #pragma unroll
        for (int tt = 0; tt < 4; ++tt) {
            int q = (wv * 4 + tt + ky) * 18 + l15 + kx;
            half8 bf = *(const half8*)(smem + xaddr(q, lhi));
            acc[tt][0] = __builtin_amdgcn_mfma_f32_16x16x32_f16(af0, bf, acc[tt][0], 0, 0, 0);
            acc[tt][1] = __builtin_amdgcn_mfma_f32_16x16x32_f16(af1, bf, acc[tt][1], 0, 0, 0);
        }
    }

    const bool bot = (lhi == 0), top = (lhi == 3);
    #pragma unroll
    for (int tt = 0; tt < 4; ++tt) {
        float aA0 = acc[tt][0][0], aA1 = acc[tt][0][1],
              aA2 = acc[tt][0][2], aA3 = acc[tt][0][3];
        float aB0 = acc[tt][1][0], aB1 = acc[tt][1][1],
              aB2 = acc[tt][1][2], aB3 = acc[tt][1][3];
        float sA0 = aA0 * aA0, sA1 = aA1 * aA1, sA2 = aA2 * aA2, sA3 = aA3 * aA3;
        float sB0 = aB0 * aB0, sB1 = aB1 * aB1, sB2 = aB2 * aB2, sB3 = aB3 * aB3;
        int up = (lane + 16) & 63, dn = (lane + 48) & 63;
        float em2 = __shfl(sB2, dn); em2 = bot ? 0.f : em2;
        float em1 = __shfl(sB3, dn); em1 = bot ? 0.f : em1;
        float ep8 = __shfl(sA0, up); ep8 = top ? 0.f : ep8;
        float ep9 = __shfl(sA1, up); ep9 = top ? 0.f : ep9;
        float s = 0.f, win = em2 + em1 + sA0 + sA1 + sA2;
        float t2, f;
        t2 = 2e-5f * win; f = fmaf(t2, fmaf(t2, 0.65625f, -0.75f), 1.0f);
        s = fmaf(aA0, f, s);  win += sA3 - em2;
        t2 = 2e-5f * win; f = fmaf(t2, fmaf(t2, 0.65625f, -0.75f), 1.0f);
        s = fmaf(aA1, f, s);  win += sB0 - em1;
        t2 = 2e-5f * win; f = fmaf(t2, fmaf(t2, 0.65625f, -0.75f), 1.0f);
        s = fmaf(aA2, f, s);  win += sB1 - sA0;
        t2 = 2e-5f * win; f = fmaf(t2, fmaf(t2, 0.65625f, -0.75f), 1.0f);
        s = fmaf(aA3, f, s);  win += sB2 - sA1;
        t2 = 2e-5f * win; f = fmaf(t2, fmaf(t2, 0.65625f, -0.75f), 1.0f);
        s = fmaf(aB0, f, s);  win += sB3 - sA2;
        t2 = 2e-5f * win; f = fmaf(t2, fmaf(t2, 0.65625f, -0.75f), 1.0f);
        s = fmaf(aB1, f, s);  win += ep8 - sA3;
        t2 = 2e-5f * win; f = fmaf(t2, fmaf(t2, 0.65625f, -0.75f), 1.0f);
        s = fmaf(aB2, f, s);  win += ep9 - sB0;
        t2 = 2e-5f * win; f = fmaf(t2, fmaf(t2, 0.65625f, -0.75f), 1.0f);
        s = fmaf(aB3, f, s);
        s += __shfl_xor(s, 16);
        s += __shfl_xor(s, 32);
        if (lhi == 0) {
            int gy = by * 16 + wv * 4 + tt, gx = bx * 16 + l15;
            float val = s * cosw[gy * CROP + gx];
            _Float16 h = (_Float16)val;
            int o = (n * CROP + gy) * CROP + gx;
            g2h[o] = h;
            g2l[o] = (_Float16)(val - (float)h);
        }
    }
}

// ---------------------------------------------------------------------------
// Stage A: row rfft, SPLIT-K x2 (as round 11). Blocks >= 2176 generate the
// G1/G3/TC twiddle tables (consumed only by LATER dispatches B1/B2/C — the
// same-stream kernel boundary orders them; fft_rows itself never reads G/TC).
// grid 2276.
// ---------------------------------------------------------------------------
__global__ __launch_bounds__(256, 4)
void fft_rows(const _Float16* __restrict__ g2h, const _Float16* __restrict__ g2l,
              const _Float16* __restrict__ TAh, const _Float16* __restrict__ TAl,
              _Float16* __restrict__ Zth, _Float16* __restrict__ Ztl,
              _Float16* __restrict__ G1h, _Float16* __restrict__ G1l,
              _Float16* __restrict__ G3h, _Float16* __restrict__ G3l,
              _Float16* __restrict__ TCh, _Float16* __restrict__ TCl)
{
    __shared__ f32x4 part[2][3][64];
    __shared__ float cs[256], sn[256];
    const int tid = threadIdx.x;

    if (blockIdx.x >= 2176) {     // ---- twiddle-gen tail blocks ----
        int tb = blockIdx.x - 2176;                    // 0..99
        {
            float s, c;
            sincosf(0.02454369260617025967f * (float)tid, &s, &c);
            cs[tid] = c; sn[tid] = s;
        }
        __syncthreads();
        if (tb < 64) {            // G1,G3: 65536 pairs, 1024/block
            int base = tb * 1024 + tid;
            #pragma unroll
            for (int i = 0; i < 4; ++i) {
                int p = base + i * 256;
                int j0 = (p & 3) * 2, lane = (p >> 2) & 63, q = p >> 8;
                int nt = q & 15, ks = q >> 4;
                int kk0 = ks * 32 + ((lane >> 4) << 3) + j0;
                int m  = nt * 16 + (lane & 15);
                int pt = kk0 >> 8;                     // uniform for the pair
                int y0 = kk0 & 255;
                int i0 = (y0 * m) & 255, i1 = ((y0 + 1) * m) & 255;
                float cv0 = cs[i0], s0 = sn[i0], cv1 = cs[i1], s1 = sn[i1];
                half2v hv, lv;
                float a0 = pt ? s0 : cv0,  a1 = pt ? s1 : cv1;          // G1
                split_pair(a0, a1, &hv, &lv);
                ((half2v*)G1h)[p] = hv; ((half2v*)G1l)[p] = lv;
                a0 = (pt ? -s0 : cv0) * (1.f/256.f);                    // G3
                a1 = (pt ? -s1 : cv1) * (1.f/256.f);
                split_pair(a0, a1, &hv, &lv);
                ((half2v*)G3h)[p] = hv; ((half2v*)G3l)[p] = lv;
            }
        } else {                  // TC: 36864 pairs, 36 blocks
            int base = (tb - 64) * 1024 + tid;
            #pragma unroll
            for (int i = 0; i < 4; ++i) {
                int p = base + i * 256;
                int j0 = (p & 3) * 2, lane = (p >> 2) & 63, q = p >> 8;
                int nt = q & 15, ks = q >> 4;
                int kk0 = ks * 32 + ((lane >> 4) << 3) + j0;
                int x  = nt * 16 + (lane & 15);
                int pt = (kk0 >= 144) ? 1 : 0;         // pair never straddles
                int k0 = kk0 - pt * 144;
                float v0 = 0.f, v1 = 0.f;
                if (k0 <= 128) {
                    float w0 = (k0 == 0 || k0 == 128) ? 1.f : 2.f;
                    int ii = (k0 * x) & 255;
                    v0 = (pt ? -w0 * sn[ii] : w0 * cs[ii]) * (1.f/256.f);
                }
                int k1 = k0 + 1;
                if (k1 <= 128) {
                    float w1w = (k1 == 0 || k1 == 128) ? 1.f : 2.f;
                    int ii = (k1 * x) & 255;
                    v1 = (pt ? -w1w * sn[ii] : w1w * cs[ii]) * (1.f/256.f);
                }
                half2v hv, lv; split_pair(v0, v1, &hv, &lv);
                ((half2v*)TCh)[p] = hv; ((half2v*)TCl)[p] = lv;
            }
        }
        return;
    }

    // ---- normal fft_rows work ----
    const int lane = tid & 63;
    const int w = tid >> 6;
    const int u = w >> 1, kh = w & 1;
    const int bsw = swz8(blockIdx.x, 2176);
    const int unit = bsw * 2 + u;                         // 0..4351
    const int mt = unit / 17, nt = unit - mt * 17;
    const int l15 = lane & 15, lhi = lane >> 4;
    const int rowA = mt * 16 + l15;

    f32x4 a0 = {}, a1 = {}, a2 = {};
    #pragma unroll
    for (int i = 0; i < 4; ++i) {
        const int ks = kh * 4 + i;
        const int ao = rowA * 256 + ks * 32 + lhi * 8;
        half8 Ah = *(const half8*)(g2h + ao);
        half8 Al = *(const half8*)(g2l + ao);
        const int bo = ((ks * 17 + nt) * 64 + lane) * 8;
        half8 Bh = *(const half8*)(TAh + bo);
        half8 Bl = *(const half8*)(TAl + bo);
        a0 = __builtin_amdgcn_mfma_f32_16x16x32_f16(Ah, Bh, a0, 0, 0, 0);
        a1 = __builtin_amdgcn_mfma_f32_16x16x32_f16(Ah, Bl, a1, 0, 0, 0);
        a2 = __builtin_amdgcn_mfma_f32_16x16x32_f16(Al, Bh, a2, 0, 0, 0);
    }
    if (kh) {
        part[u][0][lane] = a0; part[u][1][lane] = a1; part[u][2][lane] = a2;
    }
    __syncthreads();
    if (kh) return;
    a0 += part[u][0][lane]; a1 += part[u][1][lane]; a2 += part[u][2][lane];

    f32x4 acc;
    #pragma unroll
    for (int r = 0; r < 4; ++r) acc[r] = a0[r] + a1[r] + a2[r];

    const int rowD = mt * 16 + lhi * 4;
    const int n = rowD >> 8, y = rowD & 255;
    int c = nt * 16 + l15;
    int row_k = -1, koff = 0;
    if (c <= 128)                  { row_k = c;       koff = 0;   }
    else if (c >= 136 && c <= 264) { row_k = c - 136; koff = 256; }
    if (row_k >= 0) {
        half4v hv, lv;
        #pragma unroll
        for (int r = 0; r < 4; ++r) {
            float v = acc[r];
            _Float16 h = (_Float16)v;
            hv[r] = h; lv[r] = (_Float16)(v - (float)h);
        }
        size_t o = (size_t)(n * 129 + row_k) * 512 + koff + y;
        *(half4v*)(Zth + o) = hv;
        *(half4v*)(Ztl + o) = lv;
    }
}

// ---------------------------------------------------------------------------
// Stage B1: col fft + *conj(wf[0,1]). SPLIT-K x4: block = 1 unit, 4 kh-waves
// (2 ks-pairs each), LDS partial reduce. 2064 blocks, XCD-chunked.
// ---------------------------------------------------------------------------
__global__ __launch_bounds__(256, 4)
void fft_cols_mul(const _Float16* __restrict__ Zth, const _Float16* __restrict__ Ztl,
                  const _Float16* __restrict__ G1h, const _Float16* __restrict__ G1l,
                  const float* __restrict__ wf,
                  _Float16* __restrict__ Ph, _Float16* __restrict__ Pl)
{
    __shared__ f32x4 part[3][6][64];
    const int lane = threadIdx.x & 63;
    const int kh = threadIdx.x >> 6;                      // 0..3
    const int unit = swz8(blockIdx.x, 2064);              // 0..2063
    const int mt = unit >> 4, nt = unit & 15;             // mt: 0..128
    const int l15 = lane & 15, lhi = lane >> 4;
    const int rowA = mt * 16 + l15;

    f32x4 r0 = {}, r1 = {}, r2 = {}, i0 = {}, i1 = {}, i2 = {};
    #pragma unroll
    for (int i = 0; i < 2; ++i) {
        const int ks = kh * 2 + i;
        const int ao0 = rowA * 512 + ks * 32 + lhi * 8;
        half8 Ah0 = *(const half8*)(Zth + ao0);
        half8 Al0 = *(const half8*)(Ztl + ao0);
        half8 Ah1 = *(const half8*)(Zth + ao0 + 256);
        half8 Al1 = *(const half8*)(Ztl + ao0 + 256);
        const int bo0 = ((ks * 16 + nt) * 64 + lane) * 8;
        half8 B0h = *(const half8*)(G1h + bo0);            // G1[ks]
        half8 B0l = *(const half8*)(G1l + bo0);
        half8 B1h_ = *(const half8*)(G1h + bo0 + 65536);   // G1[ks+8]
        half8 B1l_ = *(const half8*)(G1l + bo0 + 65536);
        half8 nB1h = neg8(B1h_), nB1l = neg8(B1l_);        // G2[ks] = -G1[ks+8]
        r0 = __builtin_amdgcn_mfma_f32_16x16x32_f16(Ah0, B0h,  r0, 0, 0, 0);
        r1 = __builtin_amdgcn_mfma_f32_16x16x32_f16(Ah0, B0l,  r1, 0, 0, 0);
        r2 = __builtin_amdgcn_mfma_f32_16x16x32_f16(Al0, B0h,  r2, 0, 0, 0);
        r0 = __builtin_amdgcn_mfma_f32_16x16x32_f16(Ah1, B1h_, r0, 0, 0, 0);
        r1 = __builtin_amdgcn_mfma_f32_16x16x32_f16(Ah1, B1l_, r1, 0, 0, 0);
        r2 = __builtin_amdgcn_mfma_f32_16x16x32_f16(Al1, B1h_, r2, 0, 0, 0);
        i0 = __builtin_amdgcn_mfma_f32_16x16x32_f16(Ah0, nB1h, i0, 0, 0, 0);
        i1 = __builtin_amdgcn_mfma_f32_16x16x32_f16(Ah0, nB1l, i1, 0, 0, 0);
        i2 = __builtin_amdgcn_mfma_f32_16x16x32_f16(Al0, nB1h, i2, 0, 0, 0);
        i0 = __builtin_amdgcn_mfma_f32_16x16x32_f16(Ah1, B0h,  i0, 0, 0, 0);
        i1 = __builtin_amdgcn_mfma_f32_16x16x32_f16(Ah1, B0l,  i1, 0, 0, 0);
        i2 = __builtin_amdgcn_mfma_f32_16x16x32_f16(Al1, B0h,  i2, 0, 0, 0);
    }
    if (kh) {
        part[kh - 1][0][lane] = r0; part[kh - 1][1][lane] = r1;
        part[kh - 1][2][lane] = r2; part[kh - 1][3][lane] = i0;
        part[kh - 1][4][lane] = i1; part[kh - 1][5][lane] = i2;
    }
    __syncthreads();
    if (kh) return;
    #pragma unroll
    for (int g = 0; g < 3; ++g) {
        r0 += part[g][0][lane]; r1 += part[g][1][lane]; r2 += part[g][2][lane];
        i0 += part[g][3][lane]; i1 += part[g][4][lane]; i2 += part[g][5][lane];
    }

    const int rowP0 = mt * 16 + lhi * 4;
    const int m = nt * 16 + l15;
    const float* wf1 = wf + 256 * 129 * 2;
    int n_ = rowP0 / 129;
    int k_ = rowP0 - n_ * 129;
    #pragma unroll
    for (int r = 0; r < 4; ++r) {
        float wr = wf1[(m * 129 + k_) * 2 + 0];
        float wi = wf1[(m * 129 + k_) * 2 + 1];
        float fr = r0[r] + r1[r] + r2[r];
        float fi = i0[r] + i1[r] + i2[r];
        float pr = wr * fr + wi * fi;
        float pi = wr * fi - wi * fr;
        size_t o = (size_t)(rowP0 + r) * 512 + m;
        _Float16 h;
        h = (_Float16)pr; Ph[o] = h;       Pl[o] = (_Float16)(pr - (float)h);
        h = (_Float16)pi; Ph[o + 256] = h; Pl[o + 256] = (_Float16)(pi - (float)h);
        if (++k_ == 129) { k_ = 0; ++n_; }
    }
}

// ---------------------------------------------------------------------------
// Stage B2: col ifft (1/256). SPLIT-K x4 + R/I merged + ks-mirror. 2064 blocks.
// ---------------------------------------------------------------------------
__global__ __launch_bounds__(256, 4)
void fft_cols_inv(const _Float16* __restrict__ Ph, const _Float16* __restrict__ Pl,
                  const _Float16* __restrict__ G3h, const _Float16* __restrict__ G3l,
                  _Float16* __restrict__ Bth, _Float16* __restrict__ Btl)
{
    __shared__ f32x4 part[3][6][64];
    const int lane = threadIdx.x & 63;
    const int kh = threadIdx.x >> 6;                      // 0..3
    const int unit = swz8(blockIdx.x, 2064);              // 0..2063
    const int mt = unit >> 4, nt = unit & 15;
    const int l15 = lane & 15, lhi = lane >> 4;
    const int rowA = mt * 16 + l15;

    f32x4 r0 = {}, r1 = {}, r2 = {}, i0 = {}, i1 = {}, i2 = {};
    #pragma unroll
    for (int i = 0; i < 2; ++i) {
        const int ks = kh * 2 + i;
        const int ao0 = rowA * 512 + ks * 32 + lhi * 8;
        half8 Ah0 = *(const half8*)(Ph + ao0);
        half8 Al0 = *(const half8*)(Pl + ao0);
        half8 Ah1 = *(const half8*)(Ph + ao0 + 256);
        half8 Al1 = *(const half8*)(Pl + ao0 + 256);
        const int bo0 = ((ks * 16 + nt) * 64 + lane) * 8;
        half8 B0h = *(const half8*)(G3h + bo0);            // G3[ks]
        half8 B0l = *(const half8*)(G3l + bo0);
        half8 B1h_ = *(const half8*)(G3h + bo0 + 65536);   // G3[ks+8]
        half8 B1l_ = *(const half8*)(G3l + bo0 + 65536);
        half8 nB1h = neg8(B1h_), nB1l = neg8(B1l_);        // G4[ks] = -G3[ks+8]
        r0 = __builtin_amdgcn_mfma_f32_16x16x32_f16(Ah0, B0h,  r0, 0, 0, 0);
        r1 = __builtin_amdgcn_mfma_f32_16x16x32_f16(Ah0, B0l,  r1, 0, 0, 0);
        r2 = __builtin_amdgcn_mfma_f32_16x16x32_f16(Al0, B0h,  r2, 0, 0, 0);
        r0 = __builtin_amdgcn_mfma_f32_16x16x32_f16(Ah1, B1h_, r0, 0, 0, 0);
        r1 = __builtin_amdgcn_mfma_f32_16x16x32_f16(Ah1, B1l_, r1, 0, 0, 0);
        r2 = __builtin_amdgcn_mfma_f32_16x16x32_f16(Al1, B1h_, r2, 0, 0, 0);
        i0 = __builtin_amdgcn_mfma_f32_16x16x32_f16(Ah0, nB1h, i0, 0, 0, 0);
        i1 = __builtin_amdgcn_mfma_f32_16x16x32_f16(Ah0, nB1l, i1, 0, 0, 0);
        i2 = __builtin_amdgcn_mfma_f32_16x16x32_f16(Al0, nB1h, i2, 0, 0, 0);
        i0 = __builtin_amdgcn_mfma_f32_16x16x32_f16(Ah1, B0h,  i0, 0, 0, 0);
        i1 = __builtin_amdgcn_mfma_f32_16x16x32_f16(Ah1, B0l,  i1, 0, 0, 0);
        i2 = __builtin_amdgcn_mfma_f32_16x16x32_f16(Al1, B0h,  i2, 0, 0, 0);
    }
    if (kh) {
        part[kh - 1][0][lane] = r0; part[kh - 1][1][lane] = r1;
        part[kh - 1][2][lane] = r2; part[kh - 1][3][lane] = i0;
        part[kh - 1][4][lane] = i1; part[kh - 1][5][lane] = i2;
    }
    __syncthreads();
    if (kh) return;
    #pragma unroll
    for (int g = 0; g < 3; ++g) {
        r0 += part[g][0][lane]; r1 += part[g][1][lane]; r2 += part[g][2][lane];
        i0 += part[g][3][lane]; i1 += part[g][4][lane]; i2 += part[g][5][lane];
    }

    const int rowP0 = mt * 16 + lhi * 4;
    const int y = nt * 16 + l15;
    int n_ = rowP0 / 129;
    int k_ = rowP0 - n_ * 129;
    #pragma unroll
    for (int r = 0; r < 4; ++r) {
        size_t base = (size_t)(n_ * 256 + y) * 288 + k_;
        float v = r0[r] + r1[r] + r2[r];
        _Float16 h = (_Float16)v;
        Bth[base] = h;  Btl[base] = (_Float16)(v - (float)h);
        float v2 = i0[r] + i1[r] + i2[r];
        _Float16 h2 = (_Float16)v2;
        Bth[base + 144] = h2;  Btl[base + 144] = (_Float16)(v2 - (float)h2);
        if (++k_ == 129) { k_ = 0; ++n_; }
    }
}

// ---------------------------------------------------------------------------
// Stage C: row irfft (1/256). SPLIT-K x2 (kh0: ks0..4, kh1: ks5..8). 2048 blk.
// ---------------------------------------------------------------------------
__global__ __launch_bounds__(256, 4)
void irfft_rows(const _Float16* __restrict__ Bth, const _Float16* __restrict__ Btl,
                const _Float16* __restrict__ TCh, const _Float16* __restrict__ TCl,
                float* __restrict__ out)
{
    __shared__ f32x4 part[2][3][64];
    const int lane = threadIdx.x & 63;
    const int w = threadIdx.x >> 6;
    const int u = w >> 1, kh = w & 1;
    const int bsw = swz8(blockIdx.x, 2048);
    const int unit = bsw * 2 + u;                         // 0..4095
    const int mt = unit >> 4, nt = unit & 15;
    const int l15 = lane & 15, lhi = lane >> 4;
    const int rowA = mt * 16 + l15;

    f32x4 a0 = {}, a1 = {}, a2 = {};
    #pragma unroll
    for (int i = 0; i < 5; ++i) {
        if (kh && i == 4) break;
        const int ks = kh * 5 + i;
        const int ao = rowA * 288 + ks * 32 + lhi * 8;
        half8 Ah = *(const half8*)(Bth + ao);
        half8 Al = *(const half8*)(Btl + ao);
        const int bo = ((ks * 16 + nt) * 64 + lane) * 8;
        half8 Bh = *(const half8*)(TCh + bo);
        half8 Bl = *(const half8*)(TCl + bo);
        a0 = __builtin_amdgcn_mfma_f32_16x16x32_f16(Ah, Bh, a0, 0, 0, 0);
        a1 = __builtin_amdgcn_mfma_f32_16x16x32_f16(Ah, Bl, a1, 0, 0, 0);
        a2 = __builtin_amdgcn_mfma_f32_16x16x32_f16(Al, Bh, a2, 0, 0, 0);
    }
    if (kh) {
        part[u][0][lane] = a0; part[u][1][lane] = a1; part[u][2][lane] = a2;
    }
    __syncthreads();
    if (kh) return;
    a0 += part[u][0][lane]; a1 += part[u][1][lane]; a2 += part[u][2][lane];

    const int rowD = mt * 16 + lhi * 4;
    const int x = nt * 16 + l15;
    #pragma unroll
    for (int r = 0; r < 4; ++r)
        out[(size_t)(rowD + r) * 256 + x] = a0[r] + a1[r] + a2[r];
}

// ---------------------------------------------------------------------------
extern "C" void kernel_launch(void* const* d_in, const int* in_sizes, int n_in,
                              void* d_out, int out_size, void* d_ws, size_t ws_size,
                              hipStream_t stream)
{
    const float* z    = (const float*)d_in[0];
    const float* w1   = (const float*)d_in[1];
    const float* b1   = (const float*)d_in[2];
    const float* w2   = (const float*)d_in[3];
    const float* b2   = (const float*)d_in[4];
    const float* cosw = (const float*)d_in[5];
    const float* wf   = (const float*)d_in[6];
    float* out = (float*)d_out;

    char* p = (char*)d_ws;
    auto take = [&](size_t bytes) {
        char* r = p; p += (bytes + 255) & ~(size_t)255; return r;
    };
    _Float16* g2h = (_Float16*)take(4096 * 256 * 2);
    _Float16* g2l = (_Float16*)take(4096 * 256 * 2);
    _Float16* Zth = (_Float16*)take(2064 * 512 * 2);
    _Float16* Ztl = (_Float16*)take(2064 * 512 * 2);
    _Float16* Ph  = (_Float16*)take(2064 * 512 * 2);
    _Float16* Pl  = (_Float16*)take(2064 * 512 * 2);
    _Float16* Bth = (_Float16*)take(4096 * 288 * 2);
    _Float16* Btl = (_Float16*)take(4096 * 288 * 2);
    _Float16* TAh = (_Float16*)take(69632 * 2);
    _Float16* TAl = (_Float16*)take(69632 * 2);
    _Float16* G1h = (_Float16*)take(131072 * 2);
    _Float16* G1l = (_Float16*)take(131072 * 2);
    _Float16* G3h = (_Float16*)take(131072 * 2);
    _Float16* G3l = (_Float16*)take(131072 * 2);
    _Float16* TCh = (_Float16*)take(73728 * 2);
    _Float16* TCl = (_Float16*)take(73728 * 2);
    _Float16* w1pk  = (_Float16*)take(1024 * 2);
    _Float16* w2lin = (_Float16*)take(9216 * 2);

    prep<<<37, 256, 0, stream>>>(w1, w2, w1pk, w2lin, TAh, TAl);
    fused_features<<<dim3(16, 16, NS), 256, 0, stream>>>(z, w1pk, b1, w2lin, b2,
                                                         cosw, g2h, g2l);
    fft_rows<<<2276, 256, 0, stream>>>(g2h, g2l, TAh, TAl, Zth, Ztl,
                                       G1h, G1l, G3h, G3l, TCh, TCl);
    fft_cols_mul<<<2064, 256, 0, stream>>>(Zth, Ztl, G1h, G1l, wf, Ph, Pl);
    fft_cols_inv<<<2064, 256, 0, stream>>>(Ph, Pl, G3h, G3l, Bth, Btl);
    irfft_rows<<<2048, 256, 0, stream>>>(Bth, Btl, TCh, TCl, out);
}

// Round 13
// 101.138 us; speedup vs baseline: 1.3734x; 1.0009x over previous
//
#include <hip/hip_runtime.h>
#include <math.h>

#define NS   16
#define CIN  3
#define CF   32
#define CROP 256
#define KH   129

typedef _Float16 half8  __attribute__((ext_vector_type(8)));
typedef _Float16 half4v __attribute__((ext_vector_type(4)));
typedef _Float16 half2v __attribute__((ext_vector_type(2)));
typedef float    f32x4  __attribute__((ext_vector_type(4)));
typedef unsigned int u32x4 __attribute__((ext_vector_type(4)));

// exact negation of 8 packed f16 (sign-bit xor); split planes negate exactly
__device__ __forceinline__ half8 neg8(half8 v) {
    u32x4 u = __builtin_bit_cast(u32x4, v);
    u ^= (u32x4){0x80008000u, 0x80008000u, 0x80008000u, 0x80008000u};
    return __builtin_bit_cast(half8, u);
}

// bijective XCD-chunked swizzle (m204)
__device__ __forceinline__ int swz8(int b, int nb) {
    int q = nb >> 3, r = nb & 7;
    int x = b & 7, o = b >> 3;
    return (x < r ? x * (q + 1) : r * (q + 1) + (x - r) * q) + o;
}

// ---------------- LDS layout for fused_features (bytes) -------------------
#define X_OFF 0
#define Z_OFF 21504
#define LDS_BYTES 23904

__device__ __forceinline__ int xaddr(int q, int s) {
    return X_OFF + (q << 6) + ((s ^ ((q >> 1) & 3)) << 4);
}

// channel permutation: row position p <- channel c.
__device__ __forceinline__ int pi_of(int co) {
    int h = co >> 3, j = co & 7;
    return (j < 4) ? (h * 4 + j) : (16 + h * 4 + j - 4);
}
__device__ __forceinline__ int cinv_of(int p) {
    int h = (p & 15) >> 2;
    int j = (p & 3) + ((p >= 16) ? 4 : 0);
    return h * 8 + j;
}

__device__ __forceinline__ void split_pair(float v0, float v1,
                                           half2v* hp, half2v* lp) {
    _Float16 h0 = (_Float16)v0, h1 = (_Float16)v1;
    *hp = (half2v){h0, h1};
    *lp = (half2v){(_Float16)(v0 - (float)h0), (_Float16)(v1 - (float)h1)};
}

// ---------------------------------------------------------------------------
// prep: ONLY the true dependency of fused_features — weight prepack.
// (TA gen moved into fused's dispatch; G/TC gen lives in fft_rows' dispatch.)
// 3 blocks.
// ---------------------------------------------------------------------------
__global__ __launch_bounds__(256)
void prep(const float* __restrict__ w1, const float* __restrict__ w2,
          _Float16* __restrict__ w1pk, _Float16* __restrict__ w2lin)
{
    const int bid = blockIdx.x, tid = threadIdx.x;
    int base = bid * 4096;
    #pragma unroll
    for (int i = 0; i < 16; ++i) {
        int e = base + tid + i * 256;
        if (e < 9216) {           // w2[co][ci][k9] -> w2lin[k9][pi(co)][ci]
            int co = e / 288;
            int r  = e - co * 288;
            int ci = r / 9, k9 = r - ci * 9;
            w2lin[(k9 * 32 + pi_of(co)) * 32 + ci] = (_Float16)w2[e];
        } else if (e < 9344) {
            int t = e - 9216;                 // cg*64 + lane
            int lane = t & 63;
            int p = (t >> 6) * 16 + (lane & 15);
            int c = cinv_of(p);
            #pragma unroll
            for (int j = 0; j < 8; ++j) {
                int k = ((lane >> 4) << 3) + j;
                w1pk[t * 8 + j] = (k < 27) ? (_Float16)w1[c * 27 + k]
                                           : (_Float16)0.f;
            }
        }
    }
}

// ---------------------------------------------------------------------------
// Kernel 1: fused conv1+ReLU -> conv2 -> LRN -> *cos_window -> channel sum
// grid z = NS+1; z==NS tail blocks generate TA twiddles (read only by the
// LATER fft_rows dispatch — stream order guarantees completion).
// ---------------------------------------------------------------------------
__global__ __launch_bounds__(256, 5)
void fused_features(const float* __restrict__ z,
                    const _Float16* __restrict__ w1pk,
                    const float* __restrict__ b1,
                    const _Float16* __restrict__ w2lin,
                    const float* __restrict__ b2,
                    const float* __restrict__ cosw,
                    _Float16* __restrict__ g2h, _Float16* __restrict__ g2l,
                    _Float16* __restrict__ TAh, _Float16* __restrict__ TAl)
{
    __shared__ __align__(16) unsigned char smem[LDS_BYTES];
    __shared__ float cs[256], sn[256];
    _Float16* ztile = (_Float16*)(smem + Z_OFF);

    const int tid  = threadIdx.x;

    if (blockIdx.z == NS) {       // ---- TA twiddle-gen tail blocks ----
        int tb = blockIdx.y * 16 + blockIdx.x;         // 0..255
        if (tb >= 34) return;
        {
            float s, c;
            sincosf(0.02454369260617025967f * (float)tid, &s, &c);  // 2*pi/256
            cs[tid] = c; sn[tid] = s;
        }
        __syncthreads();
        int base = tb * 1024 + tid;                    // TA: 34816 pairs
        #pragma unroll
        for (int i = 0; i < 4; ++i) {
            int p = base + i * 256;
            int j0 = (p & 3) * 2, lane = (p >> 2) & 63, q = p >> 8;
            int nt = q % 17, ks = q / 17;
            int x0 = ks * 32 + ((lane >> 4) << 3) + j0;
            int c = nt * 16 + (lane & 15);
            float v0 = 0.f, v1 = 0.f;
            if (c <= 128) {
                v0 =  cs[(x0 * c) & 255];
                v1 =  cs[((x0 + 1) * c) & 255];
            } else if (c >= 136 && c <= 264) {
                int cc = c - 136;
                v0 = -sn[(x0 * cc) & 255];
                v1 = -sn[((x0 + 1) * cc) & 255];
            }
            half2v hv, lv; split_pair(v0, v1, &hv, &lv);
            ((half2v*)TAh)[p] = hv; ((half2v*)TAl)[p] = lv;
        }
        return;
    }

    const int lane = tid & 63;
    const int wv   = tid >> 6;
    const int l15  = lane & 15;
    const int lhi  = lane >> 4;

    const int n  = blockIdx.z;
    const int bx = blockIdx.x, by = blockIdx.y;
    const int fy0 = by * 16 - 1;
    const int fx0 = bx * 16 - 1;

    const int zy0 = by * 16 - 2;
    const int zx0 = bx * 16 - 2;
    for (int idx = tid; idx < CIN * 400; idx += 256) {
        int ci = idx / 400;
        int r  = idx - ci * 400;
        int yy = r / 20, xx = r - yy * 20;
        int gy = zy0 + yy, gx = zx0 + xx;
        float v = 0.0f;
        if ((unsigned)gy < CROP && (unsigned)gx < CROP)
            v = z[((n * CIN + ci) * CROP + gy) * CROP + gx];
        ztile[idx] = (_Float16)v;
    }

    half8 w1f0 = *(const half8*)(w1pk + lane * 8);
    half8 w1f1 = *(const half8*)(w1pk + 512 + lane * 8);
    float bias1v[2][4], bias2v[2][4];
    #pragma unroll
    for (int cg = 0; cg < 2; ++cg)
        #pragma unroll
        for (int r = 0; r < 4; ++r) {
            bias1v[cg][r] = b1[8 * lhi + 4 * cg + r];
            bias2v[cg][r] = b2[8 * lhi + 4 * cg + r];
        }

    int offs[8];
    #pragma unroll
    for (int j = 0; j < 8; ++j) {
        int k = lhi * 8 + j;
        int ci = k / 9, rr = k - ci * 9;
        int ky = rr / 3, kx = rr - ky * 3;
        offs[j] = (k < 27) ? (ci * 400 + ky * 20 + kx) : 0;
    }
    __syncthreads();

    const f32x4 zero4 = {0.f, 0.f, 0.f, 0.f};
    for (int t = wv; t < 21; t += 4) {
        int qp = t * 16 + l15;
        int qpc = qp < 324 ? qp : 323;
        int y = qpc / 18, x = qpc - y * 18;
        const _Float16* zb = ztile + y * 20 + x;
        half8 bfrag;
        #pragma unroll
        for (int j = 0; j < 8; ++j) bfrag[j] = zb[offs[j]];
        f32x4 d0 = __builtin_amdgcn_mfma_f32_16x16x32_f16(w1f0, bfrag, zero4, 0, 0, 0);
        f32x4 d1 = __builtin_amdgcn_mfma_f32_16x16x32_f16(w1f1, bfrag, zero4, 0, 0, 0);
        int gy = fy0 + y, gx = fx0 + x;
        bool ok = ((unsigned)gy < CROP) && ((unsigned)gx < CROP) && (qp < 324);
        half8 o8;
        #pragma unroll
        for (int r = 0; r < 4; ++r) {
            float v0 = ok ? fmaxf(d0[r] + bias1v[0][r], 0.f) : 0.f;
            float v1 = ok ? fmaxf(d1[r] + bias1v[1][r], 0.f) : 0.f;
            o8[r]     = (_Float16)v0;
            o8[4 + r] = (_Float16)v1;
        }
        *(half8*)(smem + xaddr(qp, lhi)) = o8;
    }
    __syncthreads();

    f32x4 acc[4][2];
    #pragma unroll
    for (int tt = 0; tt < 4; ++tt)
        #pragma unroll
        for (int cg = 0; cg < 2; ++cg)
            #pragma unroll
            for (int r = 0; r < 4; ++r)
                acc[tt][cg][r] = bias2v[cg][r];

    #pragma unroll
    for (int k9 = 0; k9 < 9; ++k9) {
        const int ky = k9 / 3, kx = k9 - 3 * ky;
        half8 af0 = *(const half8*)(w2lin + (k9 * 32 + l15)      * 32 + lhi * 8);
        half8 af1 = *(const half8*)(w2lin + (k9 * 32 + l15 + 16) * 32 + lhi * 8);
        #pragma unroll
        for (int tt = 0; tt < 4; ++tt) {
            int q = (wv * 4 + tt + ky) * 18 + l15 + kx;
            half8 bf = *(const half8*)(smem + xaddr(q, lhi));
            acc[tt][0] = __builtin_amdgcn_mfma_f32_16x16x32_f16(af0, bf, acc[tt][0], 0, 0, 0);
            acc[tt][1] = __builtin_amdgcn_mfma_f32_16x16x32_f16(af1, bf, acc[tt][1], 0, 0, 0);
        }
    }

    // LRN: first-order Taylor of (1+t)^-0.75 (t <= ~4e-4; t^2 term ~1e-7)
    const bool bot = (lhi == 0), top = (lhi == 3);
    #pragma unroll
    for (int tt = 0; tt < 4; ++tt) {
        float aA0 = acc[tt][0][0], aA1 = acc[tt][0][1],
              aA2 = acc[tt][0][2], aA3 = acc[tt][0][3];
        float aB0 = acc[tt][1][0], aB1 = acc[tt][1][1],
              aB2 = acc[tt][1][2], aB3 = acc[tt][1][3];
        float sA0 = aA0 * aA0, sA1 = aA1 * aA1, sA2 = aA2 * aA2, sA3 = aA3 * aA3;
        float sB0 = aB0 * aB0, sB1 = aB1 * aB1, sB2 = aB2 * aB2, sB3 = aB3 * aB3;
        int up = (lane + 16) & 63, dn = (lane + 48) & 63;
        float em2 = __shfl(sB2, dn); em2 = bot ? 0.f : em2;
        float em1 = __shfl(sB3, dn); em1 = bot ? 0.f : em1;
        float ep8 = __shfl(sA0, up); ep8 = top ? 0.f : ep8;
        float ep9 = __shfl(sA1, up); ep9 = top ? 0.f : ep9;
        float s = 0.f, win = em2 + em1 + sA0 + sA1 + sA2;
        float t2, f;
        t2 = 2e-5f * win; f = fmaf(t2, -0.75f, 1.0f);
        s = fmaf(aA0, f, s);  win += sA3 - em2;
        t2 = 2e-5f * win; f = fmaf(t2, -0.75f, 1.0f);
        s = fmaf(aA1, f, s);  win += sB0 - em1;
        t2 = 2e-5f * win; f = fmaf(t2, -0.75f, 1.0f);
        s = fmaf(aA2, f, s);  win += sB1 - sA0;
        t2 = 2e-5f * win; f = fmaf(t2, -0.75f, 1.0f);
        s = fmaf(aA3, f, s);  win += sB2 - sA1;
        t2 = 2e-5f * win; f = fmaf(t2, -0.75f, 1.0f);
        s = fmaf(aB0, f, s);  win += sB3 - sA2;
        t2 = 2e-5f * win; f = fmaf(t2, -0.75f, 1.0f);
        s = fmaf(aB1, f, s);  win += ep8 - sA3;
        t2 = 2e-5f * win; f = fmaf(t2, -0.75f, 1.0f);
        s = fmaf(aB2, f, s);  win += ep9 - sB0;
        t2 = 2e-5f * win; f = fmaf(t2, -0.75f, 1.0f);
        s = fmaf(aB3, f, s);
        s += __shfl_xor(s, 16);
        s += __shfl_xor(s, 32);
        if (lhi == 0) {
            int gy = by * 16 + wv * 4 + tt, gx = bx * 16 + l15;
            float val = s * cosw[gy * CROP + gx];
            _Float16 h = (_Float16)val;
            int o = (n * CROP + gy) * CROP + gx;
            g2h[o] = h;
            g2l[o] = (_Float16)(val - (float)h);
        }
    }
}

// ---------------------------------------------------------------------------
// Stage A: row rfft, SPLIT-K x2. Blocks >= 2176 generate G1/G3/TC tables
// (consumed only by later dispatches). grid 2276.
// ---------------------------------------------------------------------------
__global__ __launch_bounds__(256, 4)
void fft_rows(const _Float16* __restrict__ g2h, const _Float16* __restrict__ g2l,
              const _Float16* __restrict__ TAh, const _Float16* __restrict__ TAl,
              _Float16* __restrict__ Zth, _Float16* __restrict__ Ztl,
              _Float16* __restrict__ G1h, _Float16* __restrict__ G1l,
              _Float16* __restrict__ G3h, _Float16* __restrict__ G3l,
              _Float16* __restrict__ TCh, _Float16* __restrict__ TCl)
{
    __shared__ f32x4 part[2][3][64];
    __shared__ float cs[256], sn[256];
    const int tid = threadIdx.x;

    if (blockIdx.x >= 2176) {     // ---- twiddle-gen tail blocks ----
        int tb = blockIdx.x - 2176;                    // 0..99
        {
            float s, c;
            sincosf(0.02454369260617025967f * (float)tid, &s, &c);
            cs[tid] = c; sn[tid] = s;
        }
        __syncthreads();
        if (tb < 64) {            // G1,G3: 65536 pairs, 1024/block
            int base = tb * 1024 + tid;
            #pragma unroll
            for (int i = 0; i < 4; ++i) {
                int p = base + i * 256;
                int j0 = (p & 3) * 2, lane = (p >> 2) & 63, q = p >> 8;
                int nt = q & 15, ks = q >> 4;
                int kk0 = ks * 32 + ((lane >> 4) << 3) + j0;
                int m  = nt * 16 + (lane & 15);
                int pt = kk0 >> 8;                     // uniform for the pair
                int y0 = kk0 & 255;
                int i0 = (y0 * m) & 255, i1 = ((y0 + 1) * m) & 255;
                float cv0 = cs[i0], s0 = sn[i0], cv1 = cs[i1], s1 = sn[i1];
                half2v hv, lv;
                float a0 = pt ? s0 : cv0,  a1 = pt ? s1 : cv1;          // G1
                split_pair(a0, a1, &hv, &lv);
                ((half2v*)G1h)[p] = hv; ((half2v*)G1l)[p] = lv;
                a0 = (pt ? -s0 : cv0) * (1.f/256.f);                    // G3
                a1 = (pt ? -s1 : cv1) * (1.f/256.f);
                split_pair(a0, a1, &hv, &lv);
                ((half2v*)G3h)[p] = hv; ((half2v*)G3l)[p] = lv;
            }
        } else {                  // TC: 36864 pairs, 36 blocks
            int base = (tb - 64) * 1024 + tid;
            #pragma unroll
            for (int i = 0; i < 4; ++i) {
                int p = base + i * 256;
                int j0 = (p & 3) * 2, lane = (p >> 2) & 63, q = p >> 8;
                int nt = q & 15, ks = q >> 4;
                int kk0 = ks * 32 + ((lane >> 4) << 3) + j0;
                int x  = nt * 16 + (lane & 15);
                int pt = (kk0 >= 144) ? 1 : 0;         // pair never straddles
                int k0 = kk0 - pt * 144;
                float v0 = 0.f, v1 = 0.f;
                if (k0 <= 128) {
                    float w0 = (k0 == 0 || k0 == 128) ? 1.f : 2.f;
                    int ii = (k0 * x) & 255;
                    v0 = (pt ? -w0 * sn[ii] : w0 * cs[ii]) * (1.f/256.f);
                }
                int k1 = k0 + 1;
                if (k1 <= 128) {
                    float w1w = (k1 == 0 || k1 == 128) ? 1.f : 2.f;
                    int ii = (k1 * x) & 255;
                    v1 = (pt ? -w1w * sn[ii] : w1w * cs[ii]) * (1.f/256.f);
                }
                half2v hv, lv; split_pair(v0, v1, &hv, &lv);
                ((half2v*)TCh)[p] = hv; ((half2v*)TCl)[p] = lv;
            }
        }
        return;
    }

    // ---- normal fft_rows work ----
    const int lane = tid & 63;
    const int w = tid >> 6;
    const int u = w >> 1, kh = w & 1;
    const int bsw = swz8(blockIdx.x, 2176);
    const int unit = bsw * 2 + u;                         // 0..4351
    const int mt = unit / 17, nt = unit - mt * 17;
    const int l15 = lane & 15, lhi = lane >> 4;
    const int rowA = mt * 16 + l15;

    f32x4 a0 = {}, a1 = {}, a2 = {};
    #pragma unroll
    for (int i = 0; i < 4; ++i) {
        const int ks = kh * 4 + i;
        const int ao = rowA * 256 + ks * 32 + lhi * 8;
        half8 Ah = *(const half8*)(g2h + ao);
        half8 Al = *(const half8*)(g2l + ao);
        const int bo = ((ks * 17 + nt) * 64 + lane) * 8;
        half8 Bh = *(const half8*)(TAh + bo);
        half8 Bl = *(const half8*)(TAl + bo);
        a0 = __builtin_amdgcn_mfma_f32_16x16x32_f16(Ah, Bh, a0, 0, 0, 0);
        a1 = __builtin_amdgcn_mfma_f32_16x16x32_f16(Ah, Bl, a1, 0, 0, 0);
        a2 = __builtin_amdgcn_mfma_f32_16x16x32_f16(Al, Bh, a2, 0, 0, 0);
    }
    if (kh) {
        part[u][0][lane] = a0; part[u][1][lane] = a1; part[u][2][lane] = a2;
    }
    __syncthreads();
    if (kh) return;
    a0 += part[u][0][lane]; a1 += part[u][1][lane]; a2 += part[u][2][lane];

    f32x4 acc;
    #pragma unroll
    for (int r = 0; r < 4; ++r) acc[r] = a0[r] + a1[r] + a2[r];

    const int rowD = mt * 16 + lhi * 4;
    const int n = rowD >> 8, y = rowD & 255;
    int c = nt * 16 + l15;
    int row_k = -1, koff = 0;
    if (c <= 128)                  { row_k = c;       koff = 0;   }
    else if (c >= 136 && c <= 264) { row_k = c - 136; koff = 256; }
    if (row_k >= 0) {
        half4v hv, lv;
        #pragma unroll
        for (int r = 0; r < 4; ++r) {
            float v = acc[r];
            _Float16 h = (_Float16)v;
            hv[r] = h; lv[r] = (_Float16)(v - (float)h);
        }
        size_t o = (size_t)(n * 129 + row_k) * 512 + koff + y;
        *(half4v*)(Zth + o) = hv;
        *(half4v*)(Ztl + o) = lv;
    }
}

// ---------------------------------------------------------------------------
// Stage B1: col fft + *conj(wf[0,1]). SPLIT-K x4 + ks-mirror. 2064 blocks.
// ---------------------------------------------------------------------------
__global__ __launch_bounds__(256, 4)
void fft_cols_mul(const _Float16* __restrict__ Zth, const _Float16* __restrict__ Ztl,
                  const _Float16* __restrict__ G1h, const _Float16* __restrict__ G1l,
                  const float* __restrict__ wf,
                  _Float16* __restrict__ Ph, _Float16* __restrict__ Pl)
{
    __shared__ f32x4 part[3][6][64];
    const int lane = threadIdx.x & 63;
    const int kh = threadIdx.x >> 6;                      // 0..3
    const int unit = swz8(blockIdx.x, 2064);              // 0..2063
    const int mt = unit >> 4, nt = unit & 15;             // mt: 0..128
    const int l15 = lane & 15, lhi = lane >> 4;
    const int rowA = mt * 16 + l15;

    f32x4 r0 = {}, r1 = {}, r2 = {}, i0 = {}, i1 = {}, i2 = {};
    #pragma unroll
    for (int i = 0; i < 2; ++i) {
        const int ks = kh * 2 + i;
        const int ao0 = rowA * 512 + ks * 32 + lhi * 8;
        half8 Ah0 = *(const half8*)(Zth + ao0);
        half8 Al0 = *(const half8*)(Ztl + ao0);
        half8 Ah1 = *(const half8*)(Zth + ao0 + 256);
        half8 Al1 = *(const half8*)(Ztl + ao0 + 256);
        const int bo0 = ((ks * 16 + nt) * 64 + lane) * 8;
        half8 B0h = *(const half8*)(G1h + bo0);            // G1[ks]
        half8 B0l = *(const half8*)(G1l + bo0);
        half8 B1h_ = *(const half8*)(G1h + bo0 + 65536);   // G1[ks+8]
        half8 B1l_ = *(const half8*)(G1l + bo0 + 65536);
        half8 nB1h = neg8(B1h_), nB1l = neg8(B1l_);        // G2[ks] = -G1[ks+8]
        r0 = __builtin_amdgcn_mfma_f32_16x16x32_f16(Ah0, B0h,  r0, 0, 0, 0);
        r1 = __builtin_amdgcn_mfma_f32_16x16x32_f16(Ah0, B0l,  r1, 0, 0, 0);
        r2 = __builtin_amdgcn_mfma_f32_16x16x32_f16(Al0, B0h,  r2, 0, 0, 0);
        r0 = __builtin_amdgcn_mfma_f32_16x16x32_f16(Ah1, B1h_, r0, 0, 0, 0);
        r1 = __builtin_amdgcn_mfma_f32_16x16x32_f16(Ah1, B1l_, r1, 0, 0, 0);
        r2 = __builtin_amdgcn_mfma_f32_16x16x32_f16(Al1, B1h_, r2, 0, 0, 0);
        i0 = __builtin_amdgcn_mfma_f32_16x16x32_f16(Ah0, nB1h, i0, 0, 0, 0);
        i1 = __builtin_amdgcn_mfma_f32_16x16x32_f16(Ah0, nB1l, i1, 0, 0, 0);
        i2 = __builtin_amdgcn_mfma_f32_16x16x32_f16(Al0, nB1h, i2, 0, 0, 0);
        i0 = __builtin_amdgcn_mfma_f32_16x16x32_f16(Ah1, B0h,  i0, 0, 0, 0);
        i1 = __builtin_amdgcn_mfma_f32_16x16x32_f16(Ah1, B0l,  i1, 0, 0, 0);
        i2 = __builtin_amdgcn_mfma_f32_16x16x32_f16(Al1, B0h,  i2, 0, 0, 0);
    }
    if (kh) {
        part[kh - 1][0][lane] = r0; part[kh - 1][1][lane] = r1;
        part[kh - 1][2][lane] = r2; part[kh - 1][3][lane] = i0;
        part[kh - 1][4][lane] = i1; part[kh - 1][5][lane] = i2;
    }
    __syncthreads();
    if (kh) return;
    #pragma unroll
    for (int g = 0; g < 3; ++g) {
        r0 += part[g][0][lane]; r1 += part[g][1][lane]; r2 += part[g][2][lane];
        i0 += part[g][3][lane]; i1 += part[g][4][lane]; i2 += part[g][5][lane];
    }

    const int rowP0 = mt * 16 + lhi * 4;
    const int m = nt * 16 + l15;
    const float* wf1 = wf + 256 * 129 * 2;
    int n_ = rowP0 / 129;
    int k_ = rowP0 - n_ * 129;
    #pragma unroll
    for (int r = 0; r < 4; ++r) {
        float wr = wf1[(m * 129 + k_) * 2 + 0];
        float wi = wf1[(m * 129 + k_) * 2 + 1];
        float fr = r0[r] + r1[r] + r2[r];
        float fi = i0[r] + i1[r] + i2[r];
        float pr = wr * fr + wi * fi;
        float pi = wr * fi - wi * fr;
        size_t o = (size_t)(rowP0 + r) * 512 + m;
        _Float16 h;
        h = (_Float16)pr; Ph[o] = h;       Pl[o] = (_Float16)(pr - (float)h);
        h = (_Float16)pi; Ph[o + 256] = h; Pl[o + 256] = (_Float16)(pi - (float)h);
        if (++k_ == 129) { k_ = 0; ++n_; }
    }
}

// ---------------------------------------------------------------------------
// Stage B2: col ifft (1/256). SPLIT-K x4 + R/I merged + ks-mirror. 2064 blocks.
// ---------------------------------------------------------------------------
__global__ __launch_bounds__(256, 4)
void fft_cols_inv(const _Float16* __restrict__ Ph, const _Float16* __restrict__ Pl,
                  const _Float16* __restrict__ G3h, const _Float16* __restrict__ G3l,
                  _Float16* __restrict__ Bth, _Float16* __restrict__ Btl)
{
    __shared__ f32x4 part[3][6][64];
    const int lane = threadIdx.x & 63;
    const int kh = threadIdx.x >> 6;                      // 0..3
    const int unit = swz8(blockIdx.x, 2064);              // 0..2063
    const int mt = unit >> 4, nt = unit & 15;
    const int l15 = lane & 15, lhi = lane >> 4;
    const int rowA = mt * 16 + l15;

    f32x4 r0 = {}, r1 = {}, r2 = {}, i0 = {}, i1 = {}, i2 = {};
    #pragma unroll
    for (int i = 0; i < 2; ++i) {
        const int ks = kh * 2 + i;
        const int ao0 = rowA * 512 + ks * 32 + lhi * 8;
        half8 Ah0 = *(const half8*)(Ph + ao0);
        half8 Al0 = *(const half8*)(Pl + ao0);
        half8 Ah1 = *(const half8*)(Ph + ao0 + 256);
        half8 Al1 = *(const half8*)(Pl + ao0 + 256);
        const int bo0 = ((ks * 16 + nt) * 64 + lane) * 8;
        half8 B0h = *(const half8*)(G3h + bo0);            // G3[ks]
        half8 B0l = *(const half8*)(G3l + bo0);
        half8 B1h_ = *(const half8*)(G3h + bo0 + 65536);   // G3[ks+8]
        half8 B1l_ = *(const half8*)(G3l + bo0 + 65536);
        half8 nB1h = neg8(B1h_), nB1l = neg8(B1l_);        // G4[ks] = -G3[ks+8]
        r0 = __builtin_amdgcn_mfma_f32_16x16x32_f16(Ah0, B0h,  r0, 0, 0, 0);
        r1 = __builtin_amdgcn_mfma_f32_16x16x32_f16(Ah0, B0l,  r1, 0, 0, 0);
        r2 = __builtin_amdgcn_mfma_f32_16x16x32_f16(Al0, B0h,  r2, 0, 0, 0);
        r0 = __builtin_amdgcn_mfma_f32_16x16x32_f16(Ah1, B1h_, r0, 0, 0, 0);
        r1 = __builtin_amdgcn_mfma_f32_16x16x32_f16(Ah1, B1l_, r1, 0, 0, 0);
        r2 = __builtin_amdgcn_mfma_f32_16x16x32_f16(Al1, B1h_, r2, 0, 0, 0);
        i0 = __builtin_amdgcn_mfma_f32_16x16x32_f16(Ah0, nB1h, i0, 0, 0, 0);
        i1 = __builtin_amdgcn_mfma_f32_16x16x32_f16(Ah0, nB1l, i1, 0, 0, 0);
        i2 = __builtin_amdgcn_mfma_f32_16x16x32_f16(Al0, nB1h, i2, 0, 0, 0);
        i0 = __builtin_amdgcn_mfma_f32_16x16x32_f16(Ah1, B0h,  i0, 0, 0, 0);
        i1 = __builtin_amdgcn_mfma_f32_16x16x32_f16(Ah1, B0l,  i1, 0, 0, 0);
        i2 = __builtin_amdgcn_mfma_f32_16x16x32_f16(Al1, B0h,  i2, 0, 0, 0);
    }
    if (kh) {
        part[kh - 1][0][lane] = r0; part[kh - 1][1][lane] = r1;
        part[kh - 1][2][lane] = r2; part[kh - 1][3][lane] = i0;
        part[kh - 1][4][lane] = i1; part[kh - 1][5][lane] = i2;
    }
    __syncthreads();
    if (kh) return;
    #pragma unroll
    for (int g = 0; g < 3; ++g) {
        r0 += part[g][0][lane]; r1 += part[g][1][lane]; r2 += part[g][2][lane];
        i0 += part[g][3][lane]; i1 += part[g][4][lane]; i2 += part[g][5][lane];
    }

    const int rowP0 = mt * 16 + lhi * 4;
    const int y = nt * 16 + l15;
    int n_ = rowP0 / 129;
    int k_ = rowP0 - n_ * 129;
    #pragma unroll
    for (int r = 0; r < 4; ++r) {
        size_t base = (size_t)(n_ * 256 + y) * 288 + k_;
        float v = r0[r] + r1[r] + r2[r];
        _Float16 h = (_Float16)v;
        Bth[base] = h;  Btl[base] = (_Float16)(v - (float)h);
        float v2 = i0[r] + i1[r] + i2[r];
        _Float16 h2 = (_Float16)v2;
        Bth[base + 144] = h2;  Btl[base + 144] = (_Float16)(v2 - (float)h2);
        if (++k_ == 129) { k_ = 0; ++n_; }
    }
}

// ---------------------------------------------------------------------------
// Stage C: row irfft (1/256). SPLIT-K x2 (kh0: ks0..4, kh1: ks5..8). 2048 blk.
// ---------------------------------------------------------------------------
__global__ __launch_bounds__(256, 4)
void irfft_rows(const _Float16* __restrict__ Bth, const _Float16* __restrict__ Btl,
                const _Float16* __restrict__ TCh, const _Float16* __restrict__ TCl,
                float* __restrict__ out)
{
    __shared__ f32x4 part[2][3][64];
    const int lane = threadIdx.x & 63;
    const int w = threadIdx.x >> 6;
    const int u = w >> 1, kh = w & 1;
    const int bsw = swz8(blockIdx.x, 2048);
    const int unit = bsw * 2 + u;                         // 0..4095
    const int mt = unit >> 4, nt = unit & 15;
    const int l15 = lane & 15, lhi = lane >> 4;
    const int rowA = mt * 16 + l15;

    f32x4 a0 = {}, a1 = {}, a2 = {};
    #pragma unroll
    for (int i = 0; i < 5; ++i) {
        if (kh && i == 4) break;
        const int ks = kh * 5 + i;
        const int ao = rowA * 288 + ks * 32 + lhi * 8;
        half8 Ah = *(const half8*)(Bth + ao);
        half8 Al = *(const half8*)(Btl + ao);
        const int bo = ((ks * 16 + nt) * 64 + lane) * 8;
        half8 Bh = *(const half8*)(TCh + bo);
        half8 Bl = *(const half8*)(TCl + bo);
        a0 = __builtin_amdgcn_mfma_f32_16x16x32_f16(Ah, Bh, a0, 0, 0, 0);
        a1 = __builtin_amdgcn_mfma_f32_16x16x32_f16(Ah, Bl, a1, 0, 0, 0);
        a2 = __builtin_amdgcn_mfma_f32_16x16x32_f16(Al, Bh, a2, 0, 0, 0);
    }
    if (kh) {
        part[u][0][lane] = a0; part[u][1][lane] = a1; part[u][2][lane] = a2;
    }
    __syncthreads();
    if (kh) return;
    a0 += part[u][0][lane]; a1 += part[u][1][lane]; a2 += part[u][2][lane];

    const int rowD = mt * 16 + lhi * 4;
    const int x = nt * 16 + l15;
    #pragma unroll
    for (int r = 0; r < 4; ++r)
        out[(size_t)(rowD + r) * 256 + x] = a0[r] + a1[r] + a2[r];
}

// ---------------------------------------------------------------------------
extern "C" void kernel_launch(void* const* d_in, const int* in_sizes, int n_in,
                              void* d_out, int out_size, void* d_ws, size_t ws_size,
                              hipStream_t stream)
{
    const float* z    = (const float*)d_in[0];
    const float* w1   = (const float*)d_in[1];
    const float* b1   = (const float*)d_in[2];
    const float* w2   = (const float*)d_in[3];
    const float* b2   = (const float*)d_in[4];
    const float* cosw = (const float*)d_in[5];
    const float* wf   = (const float*)d_in[6];
    float* out = (float*)d_out;

    char* p = (char*)d_ws;
    auto take = [&](size_t bytes) {
        char* r = p; p += (bytes + 255) & ~(size_t)255; return r;
    };
    _Float16* g2h = (_Float16*)take(4096 * 256 * 2);
    _Float16* g2l = (_Float16*)take(4096 * 256 * 2);
    _Float16* Zth = (_Float16*)take(2064 * 512 * 2);
    _Float16* Ztl = (_Float16*)take(2064 * 512 * 2);
    _Float16* Ph  = (_Float16*)take(2064 * 512 * 2);
    _Float16* Pl  = (_Float16*)take(2064 * 512 * 2);
    _Float16* Bth = (_Float16*)take(4096 * 288 * 2);
    _Float16* Btl = (_Float16*)take(4096 * 288 * 2);
    _Float16* TAh = (_Float16*)take(69632 * 2);
    _Float16* TAl = (_Float16*)take(69632 * 2);
    _Float16* G1h = (_Float16*)take(131072 * 2);
    _Float16* G1l = (_Float16*)take(131072 * 2);
    _Float16* G3h = (_Float16*)take(131072 * 2);
    _Float16* G3l = (_Float16*)take(131072 * 2);
    _Float16* TCh = (_Float16*)take(73728 * 2);
    _Float16* TCl = (_Float16*)take(73728 * 2);
    _Float16* w1pk  = (_Float16*)take(1024 * 2);
    _Float16* w2lin = (_Float16*)take(9216 * 2);

    prep<<<3, 256, 0, stream>>>(w1, w2, w1pk, w2lin);
    fused_features<<<dim3(16, 16, NS + 1), 256, 0, stream>>>(z, w1pk, b1, w2lin,
                                                             b2, cosw, g2h, g2l,
                                                             TAh, TAl);
    fft_rows<<<2276, 256, 0, stream>>>(g2h, g2l, TAh, TAl, Zth, Ztl,
                                       G1h, G1l, G3h, G3l, TCh, TCl);
    fft_cols_mul<<<2064, 256, 0, stream>>>(Zth, Ztl, G1h, G1l, wf, Ph, Pl);
    fft_cols_inv<<<2064, 256, 0, stream>>>(Ph, Pl, G3h, G3l, Bth, Btl);
    irfft_rows<<<2048, 256, 0, stream>>>(Bth, Btl, TCh, TCl, out);
}